// Round 1
// baseline (1613.390 us; speedup 1.0000x reference)
//
#include <hip/hip_runtime.h>
#include <cstdint>
#include <cstddef>

#define H 64
#define C 7
#define F 20

static __device__ __forceinline__ int imax(int a, int b) { return a > b ? a : b; }

// ---------------- CSR construction ----------------

__global__ void k_hist(const int* __restrict__ esrc, const int* __restrict__ edst,
                       int E, int* __restrict__ cu, int* __restrict__ cm) {
  int i = blockIdx.x * 256 + threadIdx.x;
  if (i < E) {
    atomicAdd(&cu[esrc[i]], 1);
    atomicAdd(&cm[edst[i]], 1);
  }
}

__global__ __launch_bounds__(1024) void k_scan(const int* __restrict__ cnt, int n,
                                               int* __restrict__ off, int* __restrict__ cur) {
  __shared__ int wsum[16];
  int lane = threadIdx.x & 63;
  int wid  = threadIdx.x >> 6;
  int running = 0;
  int nchunk = (n + 1023) >> 10;
  for (int ch = 0; ch < nchunk; ++ch) {
    int i = (ch << 10) + (int)threadIdx.x;
    int v = (i < n) ? cnt[i] : 0;
    int incl = v;
    #pragma unroll
    for (int o = 1; o < 64; o <<= 1) {
      int t = __shfl_up(incl, o);
      if (lane >= o) incl += t;
    }
    if (lane == 63) wsum[wid] = incl;
    __syncthreads();
    if (wid == 0) {
      int wv = (lane < 16) ? wsum[lane] : 0;
      #pragma unroll
      for (int o = 1; o < 16; o <<= 1) {
        int t = __shfl_up(wv, o);
        if (lane >= o) wv += t;
      }
      if (lane < 16) wsum[lane] = wv;
    }
    __syncthreads();
    int excl = running + ((wid > 0) ? wsum[wid - 1] : 0) + incl - v;
    if (i < n) { off[i] = excl; cur[i] = excl; }
    int tot = wsum[15];
    __syncthreads();
    running += tot;
  }
  if (threadIdx.x == 0) off[n] = running;
}

__global__ void k_fill(const int* __restrict__ esrc, const int* __restrict__ edst, int E,
                       int* __restrict__ cur_u, int* __restrict__ cur_m,
                       int* __restrict__ csr_u, int* __restrict__ csr_m) {
  int i = blockIdx.x * 256 + threadIdx.x;
  if (i < E) {
    int s = esrc[i], d = edst[i];
    int pu = atomicAdd(&cur_u[s], 1);
    csr_u[pu] = d;
    int pm = atomicAdd(&cur_m[d], 1);
    csr_m[pm] = s;
  }
}

// ---------------- movie input projection ----------------
// x_movie[m,h] = sum_f movie_x[m,f]*w_movie[f,h] + b_movie[h] + movie_emb[mnid[m],h]

__global__ __launch_bounds__(256) void k_proj(
    const float* __restrict__ movie_x, const float* __restrict__ w_movie,
    const float* __restrict__ b_movie, const float* __restrict__ movie_emb,
    const int* __restrict__ mnid, float* __restrict__ x_movie, int M_) {
  __shared__ float ws_[F * H];
  for (int i = threadIdx.x; i < F * H; i += 256) ws_[i] = w_movie[i];
  __syncthreads();
  int t = blockIdx.x * 256 + threadIdx.x;
  int m = t >> 6;
  int h = t & 63;
  if (m >= M_) return;
  float acc = b_movie[h] + movie_emb[(size_t)mnid[m] * H + h];
  const float* xr = movie_x + (size_t)m * F;
  #pragma unroll
  for (int f = 0; f < F; ++f) acc += xr[f] * ws_[f * H + h];
  x_movie[(size_t)m * H + h] = acc;
}

// ---------------- combined layer2 x classifier weights ----------------
// CWul = l2_rev_Wl @ cls_W[0:64], CWur = l2_rev_Wr @ cls_W[0:64], cbu = l2_rev_bl @ cls_W[0:64]
// CWml = l2_rates_Wl @ cls_W[64:128], etc.
// cw layout: [0,448) CWul | [448,896) CWur | [896,1344) CWml | [1344,1792) CWmr | [1792,1799) cbu | [1799,1806) cbm

__global__ void k_cw(const float* __restrict__ l2u_Wl, const float* __restrict__ l2u_Wr,
                     const float* __restrict__ l2u_bl,
                     const float* __restrict__ l2m_Wl, const float* __restrict__ l2m_Wr,
                     const float* __restrict__ l2m_bl,
                     const float* __restrict__ clsW, float* __restrict__ cw) {
  int t = blockIdx.x * 256 + threadIdx.x;
  if (t < 448) {
    int k = t / C, c = t % C;
    float s = 0.f;
    for (int j = 0; j < H; ++j) s += l2u_Wl[k * H + j] * clsW[j * C + c];
    cw[t] = s;
  } else if (t < 896) {
    int u = t - 448; int k = u / C, c = u % C;
    float s = 0.f;
    for (int j = 0; j < H; ++j) s += l2u_Wr[k * H + j] * clsW[j * C + c];
    cw[t] = s;
  } else if (t < 1344) {
    int u = t - 896; int k = u / C, c = u % C;
    float s = 0.f;
    for (int j = 0; j < H; ++j) s += l2m_Wl[k * H + j] * clsW[(H + j) * C + c];
    cw[t] = s;
  } else if (t < 1792) {
    int u = t - 1344; int k = u / C, c = u % C;
    float s = 0.f;
    for (int j = 0; j < H; ++j) s += l2m_Wr[k * H + j] * clsW[(H + j) * C + c];
    cw[t] = s;
  } else if (t < 1799) {
    int c = t - 1792;
    float s = 0.f;
    for (int j = 0; j < H; ++j) s += l2u_bl[j] * clsW[j * C + c];
    cw[t] = s;
  } else if (t < 1806) {
    int c = t - 1799;
    float s = 0.f;
    for (int j = 0; j < H; ++j) s += l2m_bl[j] * clsW[(H + j) * C + c];
    cw[t] = s;
  }
}

// ---------------- fused SAGE layer-1: mean-aggregate + dual matmul + bias + relu ----------------
// out[i,:] = relu( mean_{nbr} srcT[map(nbr),:] @ Wl + bl + rootT[map(i),:] @ Wr )
// one wave handles 4 nodes: aggregation with lane=h; transform with lane=(node q2, h-quad hg).

__global__ __launch_bounds__(256) void k_sage64(
    const float* __restrict__ srcT, const int* __restrict__ src_map,
    const float* __restrict__ rootT, const int* __restrict__ root_map,
    const int* __restrict__ csr, const int* __restrict__ off,
    const float* __restrict__ Wl, const float* __restrict__ bl,
    const float* __restrict__ Wr, float* __restrict__ out,
    int N, int do_relu) {
  __shared__ __align__(16) float lwl[H * H];
  __shared__ __align__(16) float lwr[H * H];
  __shared__ __align__(16) float rows[4][4][132];  // [wave][node][agg(64) | root(64) | pad]
  for (int i = threadIdx.x; i < H * H; i += 256) { lwl[i] = Wl[i]; lwr[i] = Wr[i]; }
  int lane = threadIdx.x & 63;
  int wid  = threadIdx.x >> 6;
  int wavebase = (blockIdx.x * 4 + wid) * 4;
  __syncthreads();

  #pragma unroll
  for (int q = 0; q < 4; ++q) {
    int node = __builtin_amdgcn_readfirstlane(wavebase + q);
    float aggv = 0.f, rootv = 0.f;
    if (node < N) {
      int beg = off[node], end = off[node + 1];
      float s = 0.f;
      int j = beg;
      for (; j + 4 <= end; j += 4) {
        int a0 = csr[j + 0], a1 = csr[j + 1], a2 = csr[j + 2], a3 = csr[j + 3];
        if (src_map) { a0 = src_map[a0]; a1 = src_map[a1]; a2 = src_map[a2]; a3 = src_map[a3]; }
        float v0 = srcT[(size_t)a0 * H + lane];
        float v1 = srcT[(size_t)a1 * H + lane];
        float v2 = srcT[(size_t)a2 * H + lane];
        float v3 = srcT[(size_t)a3 * H + lane];
        s += v0; s += v1; s += v2; s += v3;
      }
      for (; j < end; ++j) {
        int a = csr[j];
        if (src_map) a = src_map[a];
        s += srcT[(size_t)a * H + lane];
      }
      aggv = s * (1.0f / (float)imax(end - beg, 1));
      int r = root_map ? root_map[node] : node;
      rootv = rootT[(size_t)r * H + lane];
    }
    rows[wid][q][lane] = aggv;
    rows[wid][q][H + lane] = rootv;
  }
  __syncthreads();

  int q2 = lane >> 4;
  int hg = lane & 15;
  int node2 = wavebase + q2;
  float4 acc = ((const float4*)bl)[hg];
  const float* rq = rows[wid][q2];
  #pragma unroll 4
  for (int k = 0; k < H; ++k) {
    float a = rq[k];
    float r = rq[H + k];
    float4 wl4 = *(const float4*)&lwl[k * H + hg * 4];
    float4 wr4 = *(const float4*)&lwr[k * H + hg * 4];
    acc.x += a * wl4.x + r * wr4.x;
    acc.y += a * wl4.y + r * wr4.y;
    acc.z += a * wl4.z + r * wr4.z;
    acc.w += a * wl4.w + r * wr4.w;
  }
  if (node2 < N) {
    if (do_relu) {
      acc.x = fmaxf(acc.x, 0.f); acc.y = fmaxf(acc.y, 0.f);
      acc.z = fmaxf(acc.z, 0.f); acc.w = fmaxf(acc.w, 0.f);
    }
    *(float4*)&out[(size_t)node2 * H + hg * 4] = acc;
  }
}

// ---------------- fused SAGE layer-2 + classifier projection (7 outputs/node) ----------------
// P[i,c] = mean_{nbr} srcT[nbr,:] @ CWl[:,c] + rootT[i,:] @ CWr[:,c] + cb[c]

__global__ __launch_bounds__(256) void k_sage7(
    const float* __restrict__ srcT, const float* __restrict__ rootT,
    const int* __restrict__ csr, const int* __restrict__ off,
    const float* __restrict__ CWl, const float* __restrict__ CWr,
    const float* __restrict__ cb, float* __restrict__ out, int N) {
  int lane = threadIdx.x & 63;
  int node = __builtin_amdgcn_readfirstlane((int)((blockIdx.x * 256 + threadIdx.x) >> 6));
  if (node >= N) return;
  float wl[C], wr[C];
  #pragma unroll
  for (int c = 0; c < C; ++c) { wl[c] = CWl[lane * C + c]; wr[c] = CWr[lane * C + c]; }
  float cbv = (lane < C) ? cb[lane] : 0.f;
  int beg = off[node], end = off[node + 1];
  float s = 0.f;
  int j = beg;
  for (; j + 4 <= end; j += 4) {
    int a0 = csr[j], a1 = csr[j + 1], a2 = csr[j + 2], a3 = csr[j + 3];
    float v0 = srcT[(size_t)a0 * H + lane];
    float v1 = srcT[(size_t)a1 * H + lane];
    float v2 = srcT[(size_t)a2 * H + lane];
    float v3 = srcT[(size_t)a3 * H + lane];
    s += v0; s += v1; s += v2; s += v3;
  }
  for (; j < end; ++j) s += srcT[(size_t)csr[j] * H + lane];
  float agg = s * (1.0f / (float)imax(end - beg, 1));
  float root = rootT[(size_t)node * H + lane];
  float t[C];
  #pragma unroll
  for (int c = 0; c < C; ++c) t[c] = agg * wl[c] + root * wr[c];
  #pragma unroll
  for (int c = 0; c < C; ++c) {
    float v = t[c];
    v += __shfl_xor(v, 1);
    v += __shfl_xor(v, 2);
    v += __shfl_xor(v, 4);
    v += __shfl_xor(v, 8);
    v += __shfl_xor(v, 16);
    v += __shfl_xor(v, 32);
    t[c] = v;
  }
  float o = t[0];
  o = (lane == 1) ? t[1] : o;
  o = (lane == 2) ? t[2] : o;
  o = (lane == 3) ? t[3] : o;
  o = (lane == 4) ? t[4] : o;
  o = (lane == 5) ? t[5] : o;
  o = (lane == 6) ? t[6] : o;
  if (lane < C) out[(size_t)node * C + lane] = o + cbv;
}

// ---------------- final edge classifier: out[e,c] = Pu[src,c] + Pm[dst,c] + b[c] ----------------

__global__ void k_final(const int* __restrict__ els, const int* __restrict__ eld,
                        const float* __restrict__ Pu, const float* __restrict__ Pm,
                        const float* __restrict__ clsb, float* __restrict__ out, int total) {
  int t = blockIdx.x * 256 + threadIdx.x;
  if (t >= total) return;
  int e = t / C, c = t - e * C;
  out[t] = Pu[(size_t)els[e] * C + c] + Pm[(size_t)eld[e] * C + c] + clsb[c];
}

extern "C" void kernel_launch(void* const* d_in, const int* in_sizes, int n_in,
                              void* d_out, int out_size, void* d_ws, size_t ws_size,
                              hipStream_t stream) {
  (void)n_in; (void)out_size; (void)ws_size;
  const int*   unid      = (const int*)d_in[0];
  const int*   mnid      = (const int*)d_in[1];
  const float* movie_x   = (const float*)d_in[2];
  const int*   e_src     = (const int*)d_in[3];
  const int*   e_dst     = (const int*)d_in[4];
  const int*   el_src    = (const int*)d_in[5];
  const int*   el_dst    = (const int*)d_in[6];
  const float* user_emb  = (const float*)d_in[7];
  const float* movie_emb = (const float*)d_in[8];
  const float* w_movie   = (const float*)d_in[9];
  const float* b_movie   = (const float*)d_in[10];
  const float* l1r_Wl    = (const float*)d_in[11];  // rates = movie-side
  const float* l1r_bl    = (const float*)d_in[12];
  const float* l1r_Wr    = (const float*)d_in[13];
  const float* l1v_Wl    = (const float*)d_in[14];  // rev = user-side
  const float* l1v_bl    = (const float*)d_in[15];
  const float* l1v_Wr    = (const float*)d_in[16];
  const float* l2r_Wl    = (const float*)d_in[17];
  const float* l2r_bl    = (const float*)d_in[18];
  const float* l2r_Wr    = (const float*)d_in[19];
  const float* l2v_Wl    = (const float*)d_in[20];
  const float* l2v_bl    = (const float*)d_in[21];
  const float* l2v_Wr    = (const float*)d_in[22];
  const float* cls_W     = (const float*)d_in[23];
  const float* cls_b     = (const float*)d_in[24];

  int U  = in_sizes[0];
  int M  = in_sizes[1];
  int E  = in_sizes[3];
  int EL = in_sizes[5];

  char* p = (char*)d_ws;
  auto alloc = [&](size_t nbytes) { char* r = p; p += (nbytes + 255) & ~(size_t)255; return r; };
  float* x_movie = (float*)alloc((size_t)M * H * 4);
  float* u1      = (float*)alloc((size_t)U * H * 4);
  float* m1      = (float*)alloc((size_t)M * H * 4);
  float* Pu      = (float*)alloc((size_t)U * C * 4);
  float* Pm      = (float*)alloc((size_t)M * C * 4);
  int*   cnt     = (int*)alloc((size_t)(U + M) * 4);
  int*   cnt_u   = cnt;
  int*   cnt_m   = cnt + U;
  int*   off_u   = (int*)alloc((size_t)(U + 1) * 4);
  int*   off_m   = (int*)alloc((size_t)(M + 1) * 4);
  int*   cur_u   = (int*)alloc((size_t)U * 4);
  int*   cur_m   = (int*)alloc((size_t)M * 4);
  int*   csr_u   = (int*)alloc((size_t)E * 4);
  int*   csr_m   = (int*)alloc((size_t)E * 4);
  float* cw      = (float*)alloc(1806 * 4);
  float* CWul = cw, *CWur = cw + 448, *CWml = cw + 896, *CWmr = cw + 1344;
  float* cbu  = cw + 1792, *cbm = cw + 1799;

  hipMemsetAsync(cnt, 0, (size_t)(U + M) * 4, stream);

  int gE = (E + 255) / 256;
  k_hist<<<gE, 256, 0, stream>>>(e_src, e_dst, E, cnt_u, cnt_m);
  k_scan<<<1, 1024, 0, stream>>>(cnt_u, U, off_u, cur_u);
  k_scan<<<1, 1024, 0, stream>>>(cnt_m, M, off_m, cur_m);
  k_fill<<<gE, 256, 0, stream>>>(e_src, e_dst, E, cur_u, cur_m, csr_u, csr_m);
  k_proj<<<(M * H + 255) / 256, 256, 0, stream>>>(movie_x, w_movie, b_movie, movie_emb, mnid, x_movie, M);
  k_cw<<<8, 256, 0, stream>>>(l2v_Wl, l2v_Wr, l2v_bl, l2r_Wl, l2r_Wr, l2r_bl, cls_W, cw);

  // layer 1: u1 = relu(sage(x_movie -> users)), m1 = relu(sage(x_user -> movies))
  k_sage64<<<(U + 15) / 16, 256, 0, stream>>>(x_movie, nullptr, user_emb, unid, csr_u, off_u,
                                              l1v_Wl, l1v_bl, l1v_Wr, u1, U, 1);
  k_sage64<<<(M + 15) / 16, 256, 0, stream>>>(user_emb, unid, x_movie, nullptr, csr_m, off_m,
                                              l1r_Wl, l1r_bl, l1r_Wr, m1, M, 1);

  // layer 2 fused with classifier projection (linear => premultiplied weights)
  k_sage7<<<(U + 3) / 4, 256, 0, stream>>>(m1, u1, csr_u, off_u, CWul, CWur, cbu, Pu, U);
  k_sage7<<<(M + 3) / 4, 256, 0, stream>>>(u1, m1, csr_m, off_m, CWml, CWmr, cbm, Pm, M);

  int total = EL * C;
  k_final<<<(total + 255) / 256, 256, 0, stream>>>(el_src, el_dst, Pu, Pm, cls_b, (float*)d_out, total);
}

// Round 2
// 1098.070 us; speedup vs baseline: 1.4693x; 1.4693x over previous
//
#include <hip/hip_runtime.h>
#include <cstdint>
#include <cstddef>

#define H 64
#define C 7
#define F 20
#define BSH 9
#define BSZ 512
#define CH 8192

static __device__ __forceinline__ int imax(int a, int b) { return a > b ? a : b; }
static __device__ __forceinline__ int imin(int a, int b) { return a < b ? a : b; }

// ---------- phase 1: coarse bucket histogram (both directions), LDS-aggregated ----------
__global__ __launch_bounds__(256) void k_bhist(const int* __restrict__ esrc,
                                               const int* __restrict__ edst, int E,
                                               int* __restrict__ gcnt_u, int* __restrict__ gcnt_m,
                                               int nbu, int nbm) {
  extern __shared__ int sh[];
  int* hu = sh;
  int* hm = sh + nbu;
  for (int i = threadIdx.x; i < nbu + nbm; i += 256) sh[i] = 0;
  __syncthreads();
  int stride = gridDim.x * 256;
  for (int i = blockIdx.x * 256 + threadIdx.x; i < E; i += stride) {
    atomicAdd(&hu[esrc[i] >> BSH], 1);
    atomicAdd(&hm[edst[i] >> BSH], 1);
  }
  __syncthreads();
  for (int i = threadIdx.x; i < nbu; i += 256) if (hu[i]) atomicAdd(&gcnt_u[i], hu[i]);
  for (int i = threadIdx.x; i < nbm; i += 256) if (hm[i]) atomicAdd(&gcnt_m[i], hm[i]);
}

// ---------- phase 2: scan bucket counts (tiny), init tails ----------
__global__ __launch_bounds__(256) void k_bscan(const int* __restrict__ gcnt_u,
                                               const int* __restrict__ gcnt_m,
                                               int nbu, int nbm, int E,
                                               int* __restrict__ boff_u, int* __restrict__ boff_m,
                                               int* __restrict__ gcur_u, int* __restrict__ gcur_m) {
  __shared__ int s[1024];
  for (int i = threadIdx.x; i < nbu; i += 256) s[i] = gcnt_u[i];
  for (int i = threadIdx.x; i < nbm; i += 256) s[512 + i] = gcnt_m[i];
  __syncthreads();
  if (threadIdx.x == 0) {
    int r = 0;
    for (int i = 0; i < nbu; ++i) { int v = s[i]; s[i] = r; r += v; }
  }
  if (threadIdx.x == 1) {
    int r = 0;
    for (int i = 0; i < nbm; ++i) { int v = s[512 + i]; s[512 + i] = r; r += v; }
  }
  __syncthreads();
  for (int i = threadIdx.x; i < nbu; i += 256) { boff_u[i] = s[i]; gcur_u[i] = s[i]; }
  for (int i = threadIdx.x; i < nbm; i += 256) { boff_m[i] = s[512 + i]; gcur_m[i] = s[512 + i]; }
  if (threadIdx.x == 0) { boff_u[nbu] = E; boff_m[nbm] = E; }
}

// ---------- phase 3: binning scatter into coarse buckets (per-block contiguous runs) ----------
// packed entry: (node & 511) << 18 | neighbor   (neighbor < 2^18)
__global__ __launch_bounds__(256) void k_bscat(const int* __restrict__ esrc,
                                               const int* __restrict__ edst, int E,
                                               int* __restrict__ gcur_u, int* __restrict__ gcur_m,
                                               unsigned int* __restrict__ pk_u,
                                               unsigned int* __restrict__ pk_m,
                                               int nbu, int nbm, int nchunks) {
  extern __shared__ int sh2[];
  int dir = (blockIdx.x >= (unsigned)nchunks) ? 1 : 0;
  int chunk = dir ? (blockIdx.x - nchunks) : blockIdx.x;
  const int* key = dir ? edst : esrc;
  const int* pay = dir ? esrc : edst;
  int* gcur = dir ? gcur_m : gcur_u;
  unsigned int* pk = dir ? pk_m : pk_u;
  int nb = dir ? nbm : nbu;
  int* cnt = sh2;
  int* base = sh2 + nb;
  int beg = chunk * CH;
  int end = imin(beg + CH, E);
  for (int i = threadIdx.x; i < nb; i += 256) cnt[i] = 0;
  __syncthreads();
  for (int i = beg + threadIdx.x; i < end; i += 256) atomicAdd(&cnt[key[i] >> BSH], 1);
  __syncthreads();
  for (int i = threadIdx.x; i < nb; i += 256) {
    int c = cnt[i];
    base[i] = c ? atomicAdd(&gcur[i], c) : 0;
    cnt[i] = 0;
  }
  __syncthreads();
  for (int i = beg + threadIdx.x; i < end; i += 256) {
    int k = key[i];
    int b = k >> BSH;
    int r = atomicAdd(&cnt[b], 1);
    pk[base[b] + r] = ((unsigned)(k & (BSZ - 1)) << 18) | (unsigned)pay[i];
  }
}

// ---------- phase 4: per-bucket CSR build (local hist + scan + scatter, confined writes) ----------
__global__ __launch_bounds__(512) void k_bbuild(const unsigned int* __restrict__ pk_u,
                                                const unsigned int* __restrict__ pk_m,
                                                const int* __restrict__ boff_u,
                                                const int* __restrict__ boff_m,
                                                int nbu, int nbm, int U_, int M_, int E,
                                                int* __restrict__ csr_u, int* __restrict__ csr_m,
                                                int* __restrict__ off_u, int* __restrict__ off_m) {
  __shared__ int hist[BSZ];
  __shared__ int cur[BSZ];
  int dir = (blockIdx.x >= (unsigned)nbu) ? 1 : 0;
  int b = dir ? (blockIdx.x - nbu) : blockIdx.x;
  const unsigned int* pk = dir ? pk_m : pk_u;
  const int* boff = dir ? boff_m : boff_u;
  int N = dir ? M_ : U_;
  int nb = dir ? nbm : nbu;
  int* csr = dir ? csr_m : csr_u;
  int* off = dir ? off_m : off_u;
  int beg = boff[b], end = boff[b + 1];
  int t = threadIdx.x;
  hist[t] = 0;
  __syncthreads();
  for (int i = beg + t; i < end; i += 512) atomicAdd(&hist[pk[i] >> 18], 1);
  __syncthreads();
  int v0 = hist[t];
  for (int o = 1; o < 512; o <<= 1) {
    int x = (t >= o) ? hist[t - o] : 0;
    __syncthreads();
    hist[t] += x;
    __syncthreads();
  }
  int excl = hist[t] - v0;       // exclusive scan value
  cur[t] = excl;
  int node = (b << BSH) + t;
  if (node < N) off[node] = beg + excl;
  if (t == 0 && b == nb - 1) off[N] = E;
  __syncthreads();
  for (int i = beg + t; i < end; i += 512) {
    unsigned int p = pk[i];
    int n = (int)(p >> 18);
    int r = atomicAdd(&cur[n], 1);
    csr[beg + r] = (int)(p & 0x3FFFFu);
  }
}

// ---------- movie input projection ----------
__global__ __launch_bounds__(256) void k_proj(
    const float* __restrict__ movie_x, const float* __restrict__ w_movie,
    const float* __restrict__ b_movie, const float* __restrict__ movie_emb,
    const int* __restrict__ mnid, float* __restrict__ x_movie, int M_) {
  __shared__ float ws_[F * H];
  for (int i = threadIdx.x; i < F * H; i += 256) ws_[i] = w_movie[i];
  __syncthreads();
  int t = blockIdx.x * 256 + threadIdx.x;
  int m = t >> 6;
  int h = t & 63;
  if (m >= M_) return;
  float acc = b_movie[h] + movie_emb[(size_t)mnid[m] * H + h];
  const float* xr = movie_x + (size_t)m * F;
  #pragma unroll
  for (int f = 0; f < F; ++f) acc += xr[f] * ws_[f * H + h];
  x_movie[(size_t)m * H + h] = acc;
}

// ---------- combined layer2 x classifier weights ----------
__global__ void k_cw(const float* __restrict__ l2u_Wl, const float* __restrict__ l2u_Wr,
                     const float* __restrict__ l2u_bl,
                     const float* __restrict__ l2m_Wl, const float* __restrict__ l2m_Wr,
                     const float* __restrict__ l2m_bl,
                     const float* __restrict__ clsW, float* __restrict__ cw) {
  int t = blockIdx.x * 256 + threadIdx.x;
  if (t < 448) {
    int k = t / C, c = t % C;
    float s = 0.f;
    for (int j = 0; j < H; ++j) s += l2u_Wl[k * H + j] * clsW[j * C + c];
    cw[t] = s;
  } else if (t < 896) {
    int u = t - 448; int k = u / C, c = u % C;
    float s = 0.f;
    for (int j = 0; j < H; ++j) s += l2u_Wr[k * H + j] * clsW[j * C + c];
    cw[t] = s;
  } else if (t < 1344) {
    int u = t - 896; int k = u / C, c = u % C;
    float s = 0.f;
    for (int j = 0; j < H; ++j) s += l2m_Wl[k * H + j] * clsW[(H + j) * C + c];
    cw[t] = s;
  } else if (t < 1792) {
    int u = t - 1344; int k = u / C, c = u % C;
    float s = 0.f;
    for (int j = 0; j < H; ++j) s += l2m_Wr[k * H + j] * clsW[(H + j) * C + c];
    cw[t] = s;
  } else if (t < 1799) {
    int c = t - 1792;
    float s = 0.f;
    for (int j = 0; j < H; ++j) s += l2u_bl[j] * clsW[j * C + c];
    cw[t] = s;
  } else if (t < 1806) {
    int c = t - 1799;
    float s = 0.f;
    for (int j = 0; j < H; ++j) s += l2m_bl[j] * clsW[(H + j) * C + c];
    cw[t] = s;
  }
}

// ---------- fused SAGE layer-1 ----------
__global__ __launch_bounds__(256) void k_sage64(
    const float* __restrict__ srcT, const int* __restrict__ src_map,
    const float* __restrict__ rootT, const int* __restrict__ root_map,
    const int* __restrict__ csr, const int* __restrict__ off,
    const float* __restrict__ Wl, const float* __restrict__ bl,
    const float* __restrict__ Wr, float* __restrict__ out,
    int N, int do_relu) {
  __shared__ __align__(16) float lwl[H * H];
  __shared__ __align__(16) float lwr[H * H];
  __shared__ __align__(16) float rows[4][4][132];
  for (int i = threadIdx.x; i < H * H; i += 256) { lwl[i] = Wl[i]; lwr[i] = Wr[i]; }
  int lane = threadIdx.x & 63;
  int wid  = threadIdx.x >> 6;
  int wavebase = (blockIdx.x * 4 + wid) * 4;
  __syncthreads();

  #pragma unroll
  for (int q = 0; q < 4; ++q) {
    int node = __builtin_amdgcn_readfirstlane(wavebase + q);
    float aggv = 0.f, rootv = 0.f;
    if (node < N) {
      int beg = off[node], end = off[node + 1];
      float s = 0.f;
      int j = beg;
      for (; j + 4 <= end; j += 4) {
        int a0 = csr[j + 0], a1 = csr[j + 1], a2 = csr[j + 2], a3 = csr[j + 3];
        if (src_map) { a0 = src_map[a0]; a1 = src_map[a1]; a2 = src_map[a2]; a3 = src_map[a3]; }
        float v0 = srcT[(size_t)a0 * H + lane];
        float v1 = srcT[(size_t)a1 * H + lane];
        float v2 = srcT[(size_t)a2 * H + lane];
        float v3 = srcT[(size_t)a3 * H + lane];
        s += v0; s += v1; s += v2; s += v3;
      }
      for (; j < end; ++j) {
        int a = csr[j];
        if (src_map) a = src_map[a];
        s += srcT[(size_t)a * H + lane];
      }
      aggv = s * (1.0f / (float)imax(end - beg, 1));
      int r = root_map ? root_map[node] : node;
      rootv = rootT[(size_t)r * H + lane];
    }
    rows[wid][q][lane] = aggv;
    rows[wid][q][H + lane] = rootv;
  }
  __syncthreads();

  int q2 = lane >> 4;
  int hg = lane & 15;
  int node2 = wavebase + q2;
  float4 acc = ((const float4*)bl)[hg];
  const float* rq = rows[wid][q2];
  #pragma unroll 4
  for (int k = 0; k < H; ++k) {
    float a = rq[k];
    float r = rq[H + k];
    float4 wl4 = *(const float4*)&lwl[k * H + hg * 4];
    float4 wr4 = *(const float4*)&lwr[k * H + hg * 4];
    acc.x += a * wl4.x + r * wr4.x;
    acc.y += a * wl4.y + r * wr4.y;
    acc.z += a * wl4.z + r * wr4.z;
    acc.w += a * wl4.w + r * wr4.w;
  }
  if (node2 < N) {
    if (do_relu) {
      acc.x = fmaxf(acc.x, 0.f); acc.y = fmaxf(acc.y, 0.f);
      acc.z = fmaxf(acc.z, 0.f); acc.w = fmaxf(acc.w, 0.f);
    }
    *(float4*)&out[(size_t)node2 * H + hg * 4] = acc;
  }
}

// ---------- project layer-1 rows to 7+pad dims for (aggregate,root) classifier parts ----------
// Z[node][0..7)  = X[node] @ CWl   (what neighbors aggregate)
// Z[node][8..15) = X[node] @ CWr   (root contribution)
__global__ __launch_bounds__(256) void k_z(const float* __restrict__ X, int N,
                                           const float* __restrict__ CWl,
                                           const float* __restrict__ CWr,
                                           float* __restrict__ Z) {
  int lane = threadIdx.x & 63;
  int node = (int)((blockIdx.x * 256 + threadIdx.x) >> 6);
  if (node >= N) return;
  float x = X[(size_t)node * H + lane];
  float tl[C], tr[C];
  #pragma unroll
  for (int c = 0; c < C; ++c) { tl[c] = x * CWl[lane * C + c]; tr[c] = x * CWr[lane * C + c]; }
  #pragma unroll
  for (int c = 0; c < C; ++c) {
    float v = tl[c];
    v += __shfl_xor(v, 1); v += __shfl_xor(v, 2); v += __shfl_xor(v, 4);
    v += __shfl_xor(v, 8); v += __shfl_xor(v, 16); v += __shfl_xor(v, 32);
    tl[c] = v;
    float w = tr[c];
    w += __shfl_xor(w, 1); w += __shfl_xor(w, 2); w += __shfl_xor(w, 4);
    w += __shfl_xor(w, 8); w += __shfl_xor(w, 16); w += __shfl_xor(w, 32);
    tr[c] = w;
  }
  if (lane < 16) {
    float sel = 0.f;
    #pragma unroll
    for (int c = 0; c < C; ++c) sel = (lane == c) ? tl[c] : sel;
    #pragma unroll
    for (int c = 0; c < C; ++c) sel = (lane == 8 + c) ? tr[c] : sel;
    Z[(size_t)node * 16 + lane] = sel;
  }
}

// ---------- layer-2 aggregation in 8-wide projected space ----------
__global__ __launch_bounds__(256) void k_agg7(const float* __restrict__ Zsrc,
                                              const float* __restrict__ Zroot,
                                              const int* __restrict__ csr,
                                              const int* __restrict__ off,
                                              const float* __restrict__ cb,
                                              float* __restrict__ P, int N) {
  int n = blockIdx.x * 256 + threadIdx.x;
  if (n >= N) return;
  int beg = off[n], end = off[n + 1];
  float acc[8] = {0.f, 0.f, 0.f, 0.f, 0.f, 0.f, 0.f, 0.f};
  for (int j = beg; j < end; ++j) {
    int a = csr[j];
    const float4* z = (const float4*)(Zsrc + (size_t)a * 16);
    float4 z0 = z[0], z1 = z[1];
    acc[0] += z0.x; acc[1] += z0.y; acc[2] += z0.z; acc[3] += z0.w;
    acc[4] += z1.x; acc[5] += z1.y; acc[6] += z1.z; acc[7] += z1.w;
  }
  float inv = 1.f / (float)imax(end - beg, 1);
  const float4* zr = (const float4*)(Zroot + (size_t)n * 16 + 8);
  float4 r0 = zr[0], r1 = zr[1];
  float4 o0, o1;
  o0.x = acc[0] * inv + r0.x + cb[0];
  o0.y = acc[1] * inv + r0.y + cb[1];
  o0.z = acc[2] * inv + r0.z + cb[2];
  o0.w = acc[3] * inv + r0.w + cb[3];
  o1.x = acc[4] * inv + r1.x + cb[4];
  o1.y = acc[5] * inv + r1.y + cb[5];
  o1.z = acc[6] * inv + r1.z + cb[6];
  o1.w = 0.f;
  float4* po = (float4*)(P + (size_t)n * 8);
  po[0] = o0;
  po[1] = o1;
}

// ---------- final edge classifier ----------
__global__ void k_final(const int* __restrict__ els, const int* __restrict__ eld,
                        const float* __restrict__ Pu, const float* __restrict__ Pm,
                        const float* __restrict__ clsb, float* __restrict__ out, int total) {
  int t = blockIdx.x * 256 + threadIdx.x;
  if (t >= total) return;
  int e = t / C, c = t - e * C;
  out[t] = Pu[(size_t)els[e] * 8 + c] + Pm[(size_t)eld[e] * 8 + c] + clsb[c];
}

extern "C" void kernel_launch(void* const* d_in, const int* in_sizes, int n_in,
                              void* d_out, int out_size, void* d_ws, size_t ws_size,
                              hipStream_t stream) {
  (void)n_in; (void)out_size; (void)ws_size;
  const int*   unid      = (const int*)d_in[0];
  const int*   mnid      = (const int*)d_in[1];
  const float* movie_x   = (const float*)d_in[2];
  const int*   e_src     = (const int*)d_in[3];
  const int*   e_dst     = (const int*)d_in[4];
  const int*   el_src    = (const int*)d_in[5];
  const int*   el_dst    = (const int*)d_in[6];
  const float* user_emb  = (const float*)d_in[7];
  const float* movie_emb = (const float*)d_in[8];
  const float* w_movie   = (const float*)d_in[9];
  const float* b_movie   = (const float*)d_in[10];
  const float* l1r_Wl    = (const float*)d_in[11];
  const float* l1r_bl    = (const float*)d_in[12];
  const float* l1r_Wr    = (const float*)d_in[13];
  const float* l1v_Wl    = (const float*)d_in[14];
  const float* l1v_bl    = (const float*)d_in[15];
  const float* l1v_Wr    = (const float*)d_in[16];
  const float* l2r_Wl    = (const float*)d_in[17];
  const float* l2r_bl    = (const float*)d_in[18];
  const float* l2r_Wr    = (const float*)d_in[19];
  const float* l2v_Wl    = (const float*)d_in[20];
  const float* l2v_bl    = (const float*)d_in[21];
  const float* l2v_Wr    = (const float*)d_in[22];
  const float* cls_W     = (const float*)d_in[23];
  const float* cls_b     = (const float*)d_in[24];

  int U  = in_sizes[0];
  int M  = in_sizes[1];
  int E  = in_sizes[3];
  int EL = in_sizes[5];

  int nbu = (U + BSZ - 1) / BSZ;   // 391
  int nbm = (M + BSZ - 1) / BSZ;   // 196
  int nchunks = (E + CH - 1) / CH; // 245

  char* p = (char*)d_ws;
  auto alloc = [&](size_t nbytes) { char* r = p; p += (nbytes + 255) & ~(size_t)255; return r; };

  // region X: x_movie during layer-1; Zm + Zu afterwards
  char* regX = alloc((size_t)M * H * 4);                 // 25.6 MB
  // region U1: pk_u+pk_m during CSR build; u1 during layer-1/k_z; Pu+Pm afterwards
  char* regU1 = alloc((size_t)U * H * 4);                // 51.2 MB
  float* m1   = (float*)alloc((size_t)M * H * 4);        // 25.6 MB
  int* csr_u  = (int*)alloc((size_t)E * 4);
  int* csr_m  = (int*)alloc((size_t)E * 4);
  int* off_u  = (int*)alloc((size_t)(U + 1) * 4);
  int* off_m  = (int*)alloc((size_t)(M + 1) * 4);
  int* gcnt   = (int*)alloc((size_t)(nbu + nbm) * 4);
  int* gcnt_u = gcnt;
  int* gcnt_m = gcnt + nbu;
  int* boff_u = (int*)alloc((size_t)(nbu + 1) * 4);
  int* boff_m = (int*)alloc((size_t)(nbm + 1) * 4);
  int* gcur_u = (int*)alloc((size_t)nbu * 4);
  int* gcur_m = (int*)alloc((size_t)nbm * 4);
  float* cw   = (float*)alloc(1806 * 4);

  float* x_movie = (float*)regX;
  float* Zm      = (float*)regX;                          // after layer-1: M*16 floats (6.4 MB)
  float* Zu      = (float*)(regX + (size_t)M * 16 * 4);   // U*16 floats (12.8 MB); total 19.2 <= 25.6
  unsigned int* pk_u = (unsigned int*)regU1;              // E*4
  unsigned int* pk_m = (unsigned int*)(regU1 + (size_t)E * 4);
  float* u1 = (float*)regU1;                              // overwrites pk after CSR build
  float* Pu = (float*)regU1;                              // after k_z: U*8 (6.4 MB)
  float* Pm = (float*)(regU1 + (size_t)U * 8 * 4);        // M*8 (3.2 MB); u1 dead by then

  float* CWul = cw, *CWur = cw + 448, *CWml = cw + 896, *CWmr = cw + 1344;
  float* cbu  = cw + 1792, *cbm = cw + 1799;

  hipMemsetAsync(gcnt, 0, (size_t)(nbu + nbm) * 4, stream);

  // ---- CSR build via bucketed counting sort ----
  k_bhist<<<256, 256, (size_t)(nbu + nbm) * 4, stream>>>(e_src, e_dst, E, gcnt_u, gcnt_m, nbu, nbm);
  k_bscan<<<1, 256, 0, stream>>>(gcnt_u, gcnt_m, nbu, nbm, E, boff_u, boff_m, gcur_u, gcur_m);
  k_bscat<<<2 * nchunks, 256, (size_t)(2 * nbu) * 4, stream>>>(e_src, e_dst, E, gcur_u, gcur_m,
                                                               pk_u, pk_m, nbu, nbm, nchunks);
  k_bbuild<<<nbu + nbm, 512, 0, stream>>>(pk_u, pk_m, boff_u, boff_m, nbu, nbm, U, M, E,
                                          csr_u, csr_m, off_u, off_m);

  // ---- small precomputes ----
  k_proj<<<(M * H + 255) / 256, 256, 0, stream>>>(movie_x, w_movie, b_movie, movie_emb, mnid, x_movie, M);
  k_cw<<<8, 256, 0, stream>>>(l2v_Wl, l2v_Wr, l2v_bl, l2r_Wl, l2r_Wr, l2r_bl, cls_W, cw);

  // ---- layer 1 (pk region is dead now; u1 overwrites it) ----
  k_sage64<<<(U + 15) / 16, 256, 0, stream>>>(x_movie, nullptr, user_emb, unid, csr_u, off_u,
                                              l1v_Wl, l1v_bl, l1v_Wr, u1, U, 1);
  k_sage64<<<(M + 15) / 16, 256, 0, stream>>>(user_emb, unid, x_movie, nullptr, csr_m, off_m,
                                              l1r_Wl, l1r_bl, l1r_Wr, m1, M, 1);

  // ---- project to 7-dim classifier space (x_movie dead; Zm/Zu overwrite regX) ----
  // Zm: l-part = m1@CWul (aggregated by users), r-part = m1@CWmr (movie root)
  k_z<<<(M * 64 + 255) / 256, 256, 0, stream>>>(m1, M, CWul, CWmr, Zm);
  // Zu: l-part = u1@CWml (aggregated by movies), r-part = u1@CWur (user root)
  k_z<<<(U * 64 + 255) / 256, 256, 0, stream>>>(u1, U, CWml, CWur, Zu);

  // ---- layer 2 aggregation in projected space (u1 dead; Pu/Pm overwrite regU1) ----
  k_agg7<<<(U + 255) / 256, 256, 0, stream>>>(Zm, Zu, csr_u, off_u, cbu, Pu, U);
  k_agg7<<<(M + 255) / 256, 256, 0, stream>>>(Zu, Zm, csr_m, off_m, cbm, Pm, M);

  // ---- final ----
  int total = EL * C;
  k_final<<<(total + 255) / 256, 256, 0, stream>>>(el_src, el_dst, Pu, Pm, cls_b, (float*)d_out, total);
}

// Round 3
// 660.338 us; speedup vs baseline: 2.4433x; 1.6629x over previous
//
#include <hip/hip_runtime.h>
#include <cstdint>
#include <cstddef>

#define H 64
#define C 7
#define F 20
#define BSH 9
#define BSZ 512
#define CH 8192
#define NW 8   // waves per sage block

typedef unsigned short u16;

static __device__ __forceinline__ int imax(int a, int b) { return a > b ? a : b; }
static __device__ __forceinline__ int imin(int a, int b) { return a < b ? a : b; }

static __device__ __forceinline__ float bf2f(u16 v) {
  union { unsigned u; float f; } x; x.u = ((unsigned)v) << 16; return x.f;
}
static __device__ __forceinline__ u16 f2bf(float f) {  // round-nearest-even
  union { float f; unsigned u; } x; x.f = f;
  unsigned r = x.u + 0x7fffu + ((x.u >> 16) & 1u);
  return (u16)(r >> 16);
}

// ---------- phase 1: coarse bucket histogram ----------
__global__ __launch_bounds__(256) void k_bhist(const int* __restrict__ esrc,
                                               const int* __restrict__ edst, int E,
                                               int* __restrict__ gcnt_u, int* __restrict__ gcnt_m,
                                               int nbu, int nbm) {
  extern __shared__ int sh[];
  int* hu = sh;
  int* hm = sh + nbu;
  for (int i = threadIdx.x; i < nbu + nbm; i += 256) sh[i] = 0;
  __syncthreads();
  int stride = gridDim.x * 256;
  for (int i = blockIdx.x * 256 + threadIdx.x; i < E; i += stride) {
    atomicAdd(&hu[esrc[i] >> BSH], 1);
    atomicAdd(&hm[edst[i] >> BSH], 1);
  }
  __syncthreads();
  for (int i = threadIdx.x; i < nbu; i += 256) if (hu[i]) atomicAdd(&gcnt_u[i], hu[i]);
  for (int i = threadIdx.x; i < nbm; i += 256) if (hm[i]) atomicAdd(&gcnt_m[i], hm[i]);
}

// ---------- phase 2: scan bucket counts ----------
__global__ __launch_bounds__(256) void k_bscan(const int* __restrict__ gcnt_u,
                                               const int* __restrict__ gcnt_m,
                                               int nbu, int nbm, int E,
                                               int* __restrict__ boff_u, int* __restrict__ boff_m,
                                               int* __restrict__ gcur_u, int* __restrict__ gcur_m) {
  __shared__ int s[1024];
  for (int i = threadIdx.x; i < nbu; i += 256) s[i] = gcnt_u[i];
  for (int i = threadIdx.x; i < nbm; i += 256) s[512 + i] = gcnt_m[i];
  __syncthreads();
  if (threadIdx.x == 0) {
    int r = 0;
    for (int i = 0; i < nbu; ++i) { int v = s[i]; s[i] = r; r += v; }
  }
  if (threadIdx.x == 1) {
    int r = 0;
    for (int i = 0; i < nbm; ++i) { int v = s[512 + i]; s[512 + i] = r; r += v; }
  }
  __syncthreads();
  for (int i = threadIdx.x; i < nbu; i += 256) { boff_u[i] = s[i]; gcur_u[i] = s[i]; }
  for (int i = threadIdx.x; i < nbm; i += 256) { boff_m[i] = s[512 + i]; gcur_m[i] = s[512 + i]; }
  if (threadIdx.x == 0) { boff_u[nbu] = E; boff_m[nbm] = E; }
}

// ---------- phase 3: binning scatter into coarse buckets ----------
__global__ __launch_bounds__(256) void k_bscat(const int* __restrict__ esrc,
                                               const int* __restrict__ edst, int E,
                                               int* __restrict__ gcur_u, int* __restrict__ gcur_m,
                                               unsigned int* __restrict__ pk_u,
                                               unsigned int* __restrict__ pk_m,
                                               int nbu, int nbm, int nchunks) {
  extern __shared__ int sh2[];
  int dir = (blockIdx.x >= (unsigned)nchunks) ? 1 : 0;
  int chunk = dir ? (blockIdx.x - nchunks) : blockIdx.x;
  const int* key = dir ? edst : esrc;
  const int* pay = dir ? esrc : edst;
  int* gcur = dir ? gcur_m : gcur_u;
  unsigned int* pk = dir ? pk_m : pk_u;
  int nb = dir ? nbm : nbu;
  int* cnt = sh2;
  int* base = sh2 + nb;
  int beg = chunk * CH;
  int end = imin(beg + CH, E);
  for (int i = threadIdx.x; i < nb; i += 256) cnt[i] = 0;
  __syncthreads();
  for (int i = beg + threadIdx.x; i < end; i += 256) atomicAdd(&cnt[key[i] >> BSH], 1);
  __syncthreads();
  for (int i = threadIdx.x; i < nb; i += 256) {
    int c = cnt[i];
    base[i] = c ? atomicAdd(&gcur[i], c) : 0;
    cnt[i] = 0;
  }
  __syncthreads();
  for (int i = beg + threadIdx.x; i < end; i += 256) {
    int k = key[i];
    int b = k >> BSH;
    int r = atomicAdd(&cnt[b], 1);
    pk[base[b] + r] = ((unsigned)(k & (BSZ - 1)) << 18) | (unsigned)pay[i];
  }
}

// ---------- phase 4: per-bucket CSR build ----------
__global__ __launch_bounds__(512) void k_bbuild(const unsigned int* __restrict__ pk_u,
                                                const unsigned int* __restrict__ pk_m,
                                                const int* __restrict__ boff_u,
                                                const int* __restrict__ boff_m,
                                                int nbu, int nbm, int U_, int M_, int E,
                                                int* __restrict__ csr_u, int* __restrict__ csr_m,
                                                int* __restrict__ off_u, int* __restrict__ off_m) {
  __shared__ int hist[BSZ];
  __shared__ int cur[BSZ];
  int dir = (blockIdx.x >= (unsigned)nbu) ? 1 : 0;
  int b = dir ? (blockIdx.x - nbu) : blockIdx.x;
  const unsigned int* pk = dir ? pk_m : pk_u;
  const int* boff = dir ? boff_m : boff_u;
  int N = dir ? M_ : U_;
  int nb = dir ? nbm : nbu;
  int* csr = dir ? csr_m : csr_u;
  int* off = dir ? off_m : off_u;
  int beg = boff[b], end = boff[b + 1];
  int t = threadIdx.x;
  hist[t] = 0;
  __syncthreads();
  for (int i = beg + t; i < end; i += 512) atomicAdd(&hist[pk[i] >> 18], 1);
  __syncthreads();
  int v0 = hist[t];
  for (int o = 1; o < 512; o <<= 1) {
    int x = (t >= o) ? hist[t - o] : 0;
    __syncthreads();
    hist[t] += x;
    __syncthreads();
  }
  int excl = hist[t] - v0;
  cur[t] = excl;
  int node = (b << BSH) + t;
  if (node < N) off[node] = beg + excl;
  if (t == 0 && b == nb - 1) off[N] = E;
  __syncthreads();
  for (int i = beg + t; i < end; i += 512) {
    unsigned int p = pk[i];
    int n = (int)(p >> 18);
    int r = atomicAdd(&cur[n], 1);
    csr[beg + r] = (int)(p & 0x3FFFFu);
  }
}

// ---------- movie input projection -> bf16 table ----------
__global__ __launch_bounds__(256) void k_proj(
    const float* __restrict__ movie_x, const float* __restrict__ w_movie,
    const float* __restrict__ b_movie, const float* __restrict__ movie_emb,
    const int* __restrict__ mnid, u16* __restrict__ xm_bf, int M_) {
  __shared__ float ws_[F * H];
  for (int i = threadIdx.x; i < F * H; i += 256) ws_[i] = w_movie[i];
  __syncthreads();
  int t = blockIdx.x * 256 + threadIdx.x;
  int m = t >> 6;
  int h = t & 63;
  if (m >= M_) return;
  float acc = b_movie[h] + movie_emb[(size_t)mnid[m] * H + h];
  const float* xr = movie_x + (size_t)m * F;
  #pragma unroll
  for (int f = 0; f < F; ++f) acc += xr[f] * ws_[f * H + h];
  xm_bf[(size_t)m * H + h] = f2bf(acc);
}

// ---------- user feature -> bf16 table (x_user = user_emb[unid]) ----------
__global__ __launch_bounds__(256) void k_cvtu(const float* __restrict__ emb,
                                              const int* __restrict__ unid,
                                              u16* __restrict__ xu_bf, int U_) {
  int t = blockIdx.x * 256 + threadIdx.x;           // one thread = 4 elems
  int total = U_ * 16;
  if (t >= total) return;
  int i = t >> 4;
  int g = t & 15;
  const float4 v = *(const float4*)(emb + (size_t)unid[i] * H + g * 4);
  ushort4 o;
  o.x = f2bf(v.x); o.y = f2bf(v.y); o.z = f2bf(v.z); o.w = f2bf(v.w);
  *(ushort4*)(xu_bf + (size_t)i * H + g * 4) = o;
}

// ---------- combined layer2 x classifier weights ----------
__global__ void k_cw(const float* __restrict__ l2u_Wl, const float* __restrict__ l2u_Wr,
                     const float* __restrict__ l2u_bl,
                     const float* __restrict__ l2m_Wl, const float* __restrict__ l2m_Wr,
                     const float* __restrict__ l2m_bl,
                     const float* __restrict__ clsW, float* __restrict__ cw) {
  int t = blockIdx.x * 256 + threadIdx.x;
  if (t < 448) {
    int k = t / C, c = t % C;
    float s = 0.f;
    for (int j = 0; j < H; ++j) s += l2u_Wl[k * H + j] * clsW[j * C + c];
    cw[t] = s;
  } else if (t < 896) {
    int u = t - 448; int k = u / C, c = u % C;
    float s = 0.f;
    for (int j = 0; j < H; ++j) s += l2u_Wr[k * H + j] * clsW[j * C + c];
    cw[t] = s;
  } else if (t < 1344) {
    int u = t - 896; int k = u / C, c = u % C;
    float s = 0.f;
    for (int j = 0; j < H; ++j) s += l2m_Wl[k * H + j] * clsW[(H + j) * C + c];
    cw[t] = s;
  } else if (t < 1792) {
    int u = t - 1344; int k = u / C, c = u % C;
    float s = 0.f;
    for (int j = 0; j < H; ++j) s += l2m_Wr[k * H + j] * clsW[(H + j) * C + c];
    cw[t] = s;
  } else if (t < 1799) {
    int c = t - 1792;
    float s = 0.f;
    for (int j = 0; j < H; ++j) s += l2u_bl[j] * clsW[j * C + c];
    cw[t] = s;
  } else if (t < 1806) {
    int c = t - 1799;
    float s = 0.f;
    for (int j = 0; j < H; ++j) s += l2m_bl[j] * clsW[(H + j) * C + c];
    cw[t] = s;
  }
}

// ---------- fused SAGE layer-1 + projection to classifier space, bf16 in/out ----------
// Z[node][0..7)  = relu(sage(node)) @ CWl   (aggregated by the other side in layer 2)
// Z[node][8..15) = relu(sage(node)) @ CWr   (this node's root contribution in layer 2)
__global__ __launch_bounds__(512, 6) void k_sage_fused(
    const u16* __restrict__ srcT, const u16* __restrict__ rootT,
    const int* __restrict__ csr, const int* __restrict__ off,
    const float* __restrict__ Wl, const float* __restrict__ bl,
    const float* __restrict__ Wr,
    const float* __restrict__ CWl, const float* __restrict__ CWr,
    u16* __restrict__ Z, int N) {
  __shared__ __align__(16) float lwl[H * H];
  __shared__ __align__(16) float lwr[H * H];
  __shared__ float lcl[H * C];
  __shared__ float lcr[H * C];
  __shared__ __align__(16) float rows[NW][4][132];
  for (int i = threadIdx.x; i < H * H; i += 512) { lwl[i] = Wl[i]; lwr[i] = Wr[i]; }
  for (int i = threadIdx.x; i < H * C; i += 512) { lcl[i] = CWl[i]; lcr[i] = CWr[i]; }
  int lane = threadIdx.x & 63;
  int wid  = threadIdx.x >> 6;
  int wavebase = (blockIdx.x * NW + wid) * 4;
  __syncthreads();

  #pragma unroll
  for (int q = 0; q < 4; ++q) {
    int node = __builtin_amdgcn_readfirstlane(wavebase + q);
    float aggv = 0.f, rootv = 0.f;
    if (node < N) {
      int beg = off[node], end = off[node + 1];
      float s = 0.f;
      int j = beg;
      for (; j + 4 <= end; j += 4) {
        int a0 = csr[j + 0], a1 = csr[j + 1], a2 = csr[j + 2], a3 = csr[j + 3];
        float v0 = bf2f(srcT[(size_t)a0 * H + lane]);
        float v1 = bf2f(srcT[(size_t)a1 * H + lane]);
        float v2 = bf2f(srcT[(size_t)a2 * H + lane]);
        float v3 = bf2f(srcT[(size_t)a3 * H + lane]);
        s += v0; s += v1; s += v2; s += v3;
      }
      for (; j < end; ++j) s += bf2f(srcT[(size_t)csr[j] * H + lane]);
      aggv = s * (1.0f / (float)imax(end - beg, 1));
      rootv = bf2f(rootT[(size_t)node * H + lane]);
    }
    rows[wid][q][lane] = aggv;
    rows[wid][q][H + lane] = rootv;
  }
  __syncthreads();

  int q2 = lane >> 4;
  int hg = lane & 15;
  int node2 = wavebase + q2;
  float4 acc = ((const float4*)bl)[hg];
  const float* rq = rows[wid][q2];
  #pragma unroll 4
  for (int k = 0; k < H; ++k) {
    float a = rq[k];
    float r = rq[H + k];
    float4 wl4 = *(const float4*)&lwl[k * H + hg * 4];
    float4 wr4 = *(const float4*)&lwr[k * H + hg * 4];
    acc.x += a * wl4.x + r * wr4.x;
    acc.y += a * wl4.y + r * wr4.y;
    acc.z += a * wl4.z + r * wr4.z;
    acc.w += a * wl4.w + r * wr4.w;
  }
  acc.x = fmaxf(acc.x, 0.f); acc.y = fmaxf(acc.y, 0.f);
  acc.z = fmaxf(acc.z, 0.f); acc.w = fmaxf(acc.w, 0.f);

  // project the 4 owned h-values onto 7+7 classifier dims, reduce over 16 lanes
  float pl[C], pr[C];
  int h0 = hg * 4;
  #pragma unroll
  for (int c = 0; c < C; ++c) {
    pl[c] = acc.x * lcl[(h0 + 0) * C + c] + acc.y * lcl[(h0 + 1) * C + c] +
            acc.z * lcl[(h0 + 2) * C + c] + acc.w * lcl[(h0 + 3) * C + c];
    pr[c] = acc.x * lcr[(h0 + 0) * C + c] + acc.y * lcr[(h0 + 1) * C + c] +
            acc.z * lcr[(h0 + 2) * C + c] + acc.w * lcr[(h0 + 3) * C + c];
  }
  #pragma unroll
  for (int c = 0; c < C; ++c) {
    float v = pl[c];
    v += __shfl_xor(v, 1); v += __shfl_xor(v, 2);
    v += __shfl_xor(v, 4); v += __shfl_xor(v, 8);
    pl[c] = v;
    float w = pr[c];
    w += __shfl_xor(w, 1); w += __shfl_xor(w, 2);
    w += __shfl_xor(w, 4); w += __shfl_xor(w, 8);
    pr[c] = w;
  }
  float zv = 0.f;
  #pragma unroll
  for (int c = 0; c < C; ++c) zv = (hg == c) ? pl[c] : zv;
  #pragma unroll
  for (int c = 0; c < C; ++c) zv = (hg == 8 + c) ? pr[c] : zv;
  if (node2 < N) Z[(size_t)node2 * 16 + hg] = f2bf(zv);
}

// ---------- layer-2 aggregation in projected bf16 space ----------
__global__ __launch_bounds__(256) void k_agg7(const u16* __restrict__ Zsrc,
                                              const u16* __restrict__ Zroot,
                                              const int* __restrict__ csr,
                                              const int* __restrict__ off,
                                              const float* __restrict__ cb,
                                              float* __restrict__ P, int N) {
  int n = blockIdx.x * 256 + threadIdx.x;
  if (n >= N) return;
  int beg = off[n], end = off[n + 1];
  float acc[8] = {0.f, 0.f, 0.f, 0.f, 0.f, 0.f, 0.f, 0.f};
  for (int j = beg; j < end; ++j) {
    int a = csr[j];
    ushort4 z0 = *(const ushort4*)(Zsrc + (size_t)a * 16);
    ushort4 z1 = *(const ushort4*)(Zsrc + (size_t)a * 16 + 4);
    acc[0] += bf2f(z0.x); acc[1] += bf2f(z0.y); acc[2] += bf2f(z0.z); acc[3] += bf2f(z0.w);
    acc[4] += bf2f(z1.x); acc[5] += bf2f(z1.y); acc[6] += bf2f(z1.z); acc[7] += bf2f(z1.w);
  }
  float inv = 1.f / (float)imax(end - beg, 1);
  ushort4 r0 = *(const ushort4*)(Zroot + (size_t)n * 16 + 8);
  ushort4 r1 = *(const ushort4*)(Zroot + (size_t)n * 16 + 12);
  float4 o0, o1;
  o0.x = acc[0] * inv + bf2f(r0.x) + cb[0];
  o0.y = acc[1] * inv + bf2f(r0.y) + cb[1];
  o0.z = acc[2] * inv + bf2f(r0.z) + cb[2];
  o0.w = acc[3] * inv + bf2f(r0.w) + cb[3];
  o1.x = acc[4] * inv + bf2f(r1.x) + cb[4];
  o1.y = acc[5] * inv + bf2f(r1.y) + cb[5];
  o1.z = acc[6] * inv + bf2f(r1.z) + cb[6];
  o1.w = 0.f;
  float4* po = (float4*)(P + (size_t)n * 8);
  po[0] = o0;
  po[1] = o1;
}

// ---------- final edge classifier ----------
__global__ void k_final(const int* __restrict__ els, const int* __restrict__ eld,
                        const float* __restrict__ Pu, const float* __restrict__ Pm,
                        const float* __restrict__ clsb, float* __restrict__ out, int total) {
  int t = blockIdx.x * 256 + threadIdx.x;
  if (t >= total) return;
  int e = t / C, c = t - e * C;
  out[t] = Pu[(size_t)els[e] * 8 + c] + Pm[(size_t)eld[e] * 8 + c] + clsb[c];
}

extern "C" void kernel_launch(void* const* d_in, const int* in_sizes, int n_in,
                              void* d_out, int out_size, void* d_ws, size_t ws_size,
                              hipStream_t stream) {
  (void)n_in; (void)out_size; (void)ws_size;
  const int*   unid      = (const int*)d_in[0];
  const int*   mnid      = (const int*)d_in[1];
  const float* movie_x   = (const float*)d_in[2];
  const int*   e_src     = (const int*)d_in[3];
  const int*   e_dst     = (const int*)d_in[4];
  const int*   el_src    = (const int*)d_in[5];
  const int*   el_dst    = (const int*)d_in[6];
  const float* user_emb  = (const float*)d_in[7];
  const float* movie_emb = (const float*)d_in[8];
  const float* w_movie   = (const float*)d_in[9];
  const float* b_movie   = (const float*)d_in[10];
  const float* l1r_Wl    = (const float*)d_in[11];
  const float* l1r_bl    = (const float*)d_in[12];
  const float* l1r_Wr    = (const float*)d_in[13];
  const float* l1v_Wl    = (const float*)d_in[14];
  const float* l1v_bl    = (const float*)d_in[15];
  const float* l1v_Wr    = (const float*)d_in[16];
  const float* l2r_Wl    = (const float*)d_in[17];
  const float* l2r_bl    = (const float*)d_in[18];
  const float* l2r_Wr    = (const float*)d_in[19];
  const float* l2v_Wl    = (const float*)d_in[20];
  const float* l2v_bl    = (const float*)d_in[21];
  const float* l2v_Wr    = (const float*)d_in[22];
  const float* cls_W     = (const float*)d_in[23];
  const float* cls_b     = (const float*)d_in[24];

  int U  = in_sizes[0];
  int M  = in_sizes[1];
  int E  = in_sizes[3];
  int EL = in_sizes[5];

  int nbu = (U + BSZ - 1) / BSZ;
  int nbm = (M + BSZ - 1) / BSZ;
  int nchunks = (E + CH - 1) / CH;

  char* p = (char*)d_ws;
  auto alloc = [&](size_t nbytes) { char* r = p; p += (nbytes + 255) & ~(size_t)255; return r; };

  u16*   xm_bf  = (u16*)alloc((size_t)M * H * 2);
  u16*   xu_bf  = (u16*)alloc((size_t)U * H * 2);
  u16*   Zu     = (u16*)alloc((size_t)U * 16 * 2);
  u16*   Zm     = (u16*)alloc((size_t)M * 16 * 2);
  float* Pu     = (float*)alloc((size_t)U * 8 * 4);
  float* Pm     = (float*)alloc((size_t)M * 8 * 4);
  int*   csr_u  = (int*)alloc((size_t)E * 4);
  int*   csr_m  = (int*)alloc((size_t)E * 4);
  int*   off_u  = (int*)alloc((size_t)(U + 1) * 4);
  int*   off_m  = (int*)alloc((size_t)(M + 1) * 4);
  unsigned int* pk_u = (unsigned int*)alloc((size_t)E * 4);
  unsigned int* pk_m = (unsigned int*)alloc((size_t)E * 4);
  int*   gcnt   = (int*)alloc((size_t)(nbu + nbm) * 4);
  int*   gcnt_u = gcnt;
  int*   gcnt_m = gcnt + nbu;
  int*   boff_u = (int*)alloc((size_t)(nbu + 1) * 4);
  int*   boff_m = (int*)alloc((size_t)(nbm + 1) * 4);
  int*   gcur_u = (int*)alloc((size_t)nbu * 4);
  int*   gcur_m = (int*)alloc((size_t)nbm * 4);
  float* cw     = (float*)alloc(1806 * 4);
  float* CWul = cw, *CWur = cw + 448, *CWml = cw + 896, *CWmr = cw + 1344;
  float* cbu  = cw + 1792, *cbm = cw + 1799;

  hipMemsetAsync(gcnt, 0, (size_t)(nbu + nbm) * 4, stream);

  // ---- CSR build ----
  k_bhist<<<256, 256, (size_t)(nbu + nbm) * 4, stream>>>(e_src, e_dst, E, gcnt_u, gcnt_m, nbu, nbm);
  k_bscan<<<1, 256, 0, stream>>>(gcnt_u, gcnt_m, nbu, nbm, E, boff_u, boff_m, gcur_u, gcur_m);
  k_bscat<<<2 * nchunks, 256, (size_t)(2 * nbu) * 4, stream>>>(e_src, e_dst, E, gcur_u, gcur_m,
                                                               pk_u, pk_m, nbu, nbm, nchunks);
  k_bbuild<<<nbu + nbm, 512, 0, stream>>>(pk_u, pk_m, boff_u, boff_m, nbu, nbm, U, M, E,
                                          csr_u, csr_m, off_u, off_m);

  // ---- feature tables (bf16) + combined classifier weights ----
  k_proj<<<(M * H + 255) / 256, 256, 0, stream>>>(movie_x, w_movie, b_movie, movie_emb, mnid, xm_bf, M);
  k_cvtu<<<(U * 16 + 255) / 256, 256, 0, stream>>>(user_emb, unid, xu_bf, U);
  k_cw<<<8, 256, 0, stream>>>(l2v_Wl, l2v_Wr, l2v_bl, l2r_Wl, l2r_Wr, l2r_bl, cls_W, cw);

  // ---- layer 1 fused with projection to classifier space ----
  // user side: u1 = relu(sage(x_movie -> user)); Zu = [u1@CWml | u1@CWur]
  k_sage_fused<<<(U + NW * 4 - 1) / (NW * 4), 512, 0, stream>>>(
      xm_bf, xu_bf, csr_u, off_u, l1v_Wl, l1v_bl, l1v_Wr, CWml, CWur, Zu, U);
  // movie side: m1 = relu(sage(x_user -> movie)); Zm = [m1@CWul | m1@CWmr]
  k_sage_fused<<<(M + NW * 4 - 1) / (NW * 4), 512, 0, stream>>>(
      xu_bf, xm_bf, csr_m, off_m, l1r_Wl, l1r_bl, l1r_Wr, CWul, CWmr, Zm, M);

  // ---- layer 2 aggregation in projected space ----
  k_agg7<<<(U + 255) / 256, 256, 0, stream>>>(Zm, Zu, csr_u, off_u, cbu, Pu, U);
  k_agg7<<<(M + 255) / 256, 256, 0, stream>>>(Zu, Zm, csr_m, off_m, cbm, Pm, M);

  // ---- final ----
  int total = EL * C;
  k_final<<<(total + 255) / 256, 256, 0, stream>>>(el_src, el_dst, Pu, Pm, cls_b, (float*)d_out, total);
}

// Round 4
// 609.579 us; speedup vs baseline: 2.6467x; 1.0833x over previous
//
#include <hip/hip_runtime.h>
#include <cstdint>
#include <cstddef>

#define H 64
#define C 7
#define F 20
#define BSH 9
#define BSZ 512
#define CH 8192

typedef unsigned short u16;
typedef __attribute__((ext_vector_type(8))) short bf16x8;
typedef __attribute__((ext_vector_type(4))) float f32x4;

static __device__ __forceinline__ int imax(int a, int b) { return a > b ? a : b; }
static __device__ __forceinline__ int imin(int a, int b) { return a < b ? a : b; }

static __device__ __forceinline__ float bf2f(u16 v) {
  union { unsigned u; float f; } x; x.u = ((unsigned)v) << 16; return x.f;
}
static __device__ __forceinline__ u16 f2bf(float f) {  // round-nearest-even
  union { float f; unsigned u; } x; x.f = f;
  unsigned r = x.u + 0x7fffu + ((x.u >> 16) & 1u);
  return (u16)(r >> 16);
}
static __device__ __forceinline__ int pack2bf(float a, float b) {
  return (int)f2bf(a) | ((int)f2bf(b) << 16);
}

// ---------- phase 1: coarse bucket histogram ----------
__global__ __launch_bounds__(256) void k_bhist(const int* __restrict__ esrc,
                                               const int* __restrict__ edst, int E,
                                               int* __restrict__ gcnt_u, int* __restrict__ gcnt_m,
                                               int nbu, int nbm) {
  extern __shared__ int sh[];
  int* hu = sh;
  int* hm = sh + nbu;
  for (int i = threadIdx.x; i < nbu + nbm; i += 256) sh[i] = 0;
  __syncthreads();
  int stride = gridDim.x * 256;
  for (int i = blockIdx.x * 256 + threadIdx.x; i < E; i += stride) {
    atomicAdd(&hu[esrc[i] >> BSH], 1);
    atomicAdd(&hm[edst[i] >> BSH], 1);
  }
  __syncthreads();
  for (int i = threadIdx.x; i < nbu; i += 256) if (hu[i]) atomicAdd(&gcnt_u[i], hu[i]);
  for (int i = threadIdx.x; i < nbm; i += 256) if (hm[i]) atomicAdd(&gcnt_m[i], hm[i]);
}

// ---------- phase 2: scan bucket counts ----------
__global__ __launch_bounds__(256) void k_bscan(const int* __restrict__ gcnt_u,
                                               const int* __restrict__ gcnt_m,
                                               int nbu, int nbm, int E,
                                               int* __restrict__ boff_u, int* __restrict__ boff_m,
                                               int* __restrict__ gcur_u, int* __restrict__ gcur_m) {
  __shared__ int s[1024];
  for (int i = threadIdx.x; i < nbu; i += 256) s[i] = gcnt_u[i];
  for (int i = threadIdx.x; i < nbm; i += 256) s[512 + i] = gcnt_m[i];
  __syncthreads();
  if (threadIdx.x == 0) {
    int r = 0;
    for (int i = 0; i < nbu; ++i) { int v = s[i]; s[i] = r; r += v; }
  }
  if (threadIdx.x == 1) {
    int r = 0;
    for (int i = 0; i < nbm; ++i) { int v = s[512 + i]; s[512 + i] = r; r += v; }
  }
  __syncthreads();
  for (int i = threadIdx.x; i < nbu; i += 256) { boff_u[i] = s[i]; gcur_u[i] = s[i]; }
  for (int i = threadIdx.x; i < nbm; i += 256) { boff_m[i] = s[512 + i]; gcur_m[i] = s[512 + i]; }
  if (threadIdx.x == 0) { boff_u[nbu] = E; boff_m[nbm] = E; }
}

// ---------- phase 3: binning scatter into coarse buckets ----------
__global__ __launch_bounds__(256) void k_bscat(const int* __restrict__ esrc,
                                               const int* __restrict__ edst, int E,
                                               int* __restrict__ gcur_u, int* __restrict__ gcur_m,
                                               unsigned int* __restrict__ pk_u,
                                               unsigned int* __restrict__ pk_m,
                                               int nbu, int nbm, int nchunks) {
  extern __shared__ int sh2[];
  int dir = (blockIdx.x >= (unsigned)nchunks) ? 1 : 0;
  int chunk = dir ? (blockIdx.x - nchunks) : blockIdx.x;
  const int* key = dir ? edst : esrc;
  const int* pay = dir ? esrc : edst;
  int* gcur = dir ? gcur_m : gcur_u;
  unsigned int* pk = dir ? pk_m : pk_u;
  int nb = dir ? nbm : nbu;
  int* cnt = sh2;
  int* base = sh2 + nb;
  int beg = chunk * CH;
  int end = imin(beg + CH, E);
  for (int i = threadIdx.x; i < nb; i += 256) cnt[i] = 0;
  __syncthreads();
  for (int i = beg + threadIdx.x; i < end; i += 256) atomicAdd(&cnt[key[i] >> BSH], 1);
  __syncthreads();
  for (int i = threadIdx.x; i < nb; i += 256) {
    int c = cnt[i];
    base[i] = c ? atomicAdd(&gcur[i], c) : 0;
    cnt[i] = 0;
  }
  __syncthreads();
  for (int i = beg + threadIdx.x; i < end; i += 256) {
    int k = key[i];
    int b = k >> BSH;
    int r = atomicAdd(&cnt[b], 1);
    pk[base[b] + r] = ((unsigned)(k & (BSZ - 1)) << 18) | (unsigned)pay[i];
  }
}

// ---------- phase 4: per-bucket CSR build ----------
__global__ __launch_bounds__(512) void k_bbuild(const unsigned int* __restrict__ pk_u,
                                                const unsigned int* __restrict__ pk_m,
                                                const int* __restrict__ boff_u,
                                                const int* __restrict__ boff_m,
                                                int nbu, int nbm, int U_, int M_, int E,
                                                int* __restrict__ csr_u, int* __restrict__ csr_m,
                                                int* __restrict__ off_u, int* __restrict__ off_m) {
  __shared__ int hist[BSZ];
  __shared__ int cur[BSZ];
  int dir = (blockIdx.x >= (unsigned)nbu) ? 1 : 0;
  int b = dir ? (blockIdx.x - nbu) : blockIdx.x;
  const unsigned int* pk = dir ? pk_m : pk_u;
  const int* boff = dir ? boff_m : boff_u;
  int N = dir ? M_ : U_;
  int nb = dir ? nbm : nbu;
  int* csr = dir ? csr_m : csr_u;
  int* off = dir ? off_m : off_u;
  int beg = boff[b], end = boff[b + 1];
  int t = threadIdx.x;
  hist[t] = 0;
  __syncthreads();
  for (int i = beg + t; i < end; i += 512) atomicAdd(&hist[pk[i] >> 18], 1);
  __syncthreads();
  int v0 = hist[t];
  for (int o = 1; o < 512; o <<= 1) {
    int x = (t >= o) ? hist[t - o] : 0;
    __syncthreads();
    hist[t] += x;
    __syncthreads();
  }
  int excl = hist[t] - v0;
  cur[t] = excl;
  int node = (b << BSH) + t;
  if (node < N) off[node] = beg + excl;
  if (t == 0 && b == nb - 1) off[N] = E;
  __syncthreads();
  for (int i = beg + t; i < end; i += 512) {
    unsigned int p = pk[i];
    int n = (int)(p >> 18);
    int r = atomicAdd(&cur[n], 1);
    csr[beg + r] = (int)(p & 0x3FFFFu);
  }
}

// ---------- movie input projection -> bf16 table ----------
__global__ __launch_bounds__(256) void k_proj(
    const float* __restrict__ movie_x, const float* __restrict__ w_movie,
    const float* __restrict__ b_movie, const float* __restrict__ movie_emb,
    const int* __restrict__ mnid, u16* __restrict__ xm_bf, int M_) {
  __shared__ float ws_[F * H];
  for (int i = threadIdx.x; i < F * H; i += 256) ws_[i] = w_movie[i];
  __syncthreads();
  int t = blockIdx.x * 256 + threadIdx.x;
  int m = t >> 6;
  int h = t & 63;
  if (m >= M_) return;
  float acc = b_movie[h] + movie_emb[(size_t)mnid[m] * H + h];
  const float* xr = movie_x + (size_t)m * F;
  #pragma unroll
  for (int f = 0; f < F; ++f) acc += xr[f] * ws_[f * H + h];
  xm_bf[(size_t)m * H + h] = f2bf(acc);
}

// ---------- user feature -> bf16 table ----------
__global__ __launch_bounds__(256) void k_cvtu(const float* __restrict__ emb,
                                              const int* __restrict__ unid,
                                              u16* __restrict__ xu_bf, int U_) {
  int t = blockIdx.x * 256 + threadIdx.x;
  int total = U_ * 16;
  if (t >= total) return;
  int i = t >> 4;
  int g = t & 15;
  const float4 v = *(const float4*)(emb + (size_t)unid[i] * H + g * 4);
  ushort4 o;
  o.x = f2bf(v.x); o.y = f2bf(v.y); o.z = f2bf(v.z); o.w = f2bf(v.w);
  *(ushort4*)(xu_bf + (size_t)i * H + g * 4) = o;
}

// ---------- combined layer2 x classifier weights ----------
__global__ void k_cw(const float* __restrict__ l2u_Wl, const float* __restrict__ l2u_Wr,
                     const float* __restrict__ l2u_bl,
                     const float* __restrict__ l2m_Wl, const float* __restrict__ l2m_Wr,
                     const float* __restrict__ l2m_bl,
                     const float* __restrict__ clsW, float* __restrict__ cw) {
  int t = blockIdx.x * 256 + threadIdx.x;
  if (t < 448) {
    int k = t / C, c = t % C;
    float s = 0.f;
    for (int j = 0; j < H; ++j) s += l2u_Wl[k * H + j] * clsW[j * C + c];
    cw[t] = s;
  } else if (t < 896) {
    int u = t - 448; int k = u / C, c = u % C;
    float s = 0.f;
    for (int j = 0; j < H; ++j) s += l2u_Wr[k * H + j] * clsW[j * C + c];
    cw[t] = s;
  } else if (t < 1344) {
    int u = t - 896; int k = u / C, c = u % C;
    float s = 0.f;
    for (int j = 0; j < H; ++j) s += l2m_Wl[k * H + j] * clsW[(H + j) * C + c];
    cw[t] = s;
  } else if (t < 1792) {
    int u = t - 1344; int k = u / C, c = u % C;
    float s = 0.f;
    for (int j = 0; j < H; ++j) s += l2m_Wr[k * H + j] * clsW[(H + j) * C + c];
    cw[t] = s;
  } else if (t < 1799) {
    int c = t - 1792;
    float s = 0.f;
    for (int j = 0; j < H; ++j) s += l2u_bl[j] * clsW[j * C + c];
    cw[t] = s;
  } else if (t < 1806) {
    int c = t - 1799;
    float s = 0.f;
    for (int j = 0; j < H; ++j) s += l2m_bl[j] * clsW[(H + j) * C + c];
    cw[t] = s;
  }
}

// ---------- per-node leftover gather (degree > 32, rare) ----------
static __device__ __forceinline__ void gather_extra(
    const u16* __restrict__ srcT, const int* __restrict__ csr,
    int jb, int en, int l5, int slot, float& ax, float& ay) {
  for (int j = jb; j < en; j += 32) {
    int bt = en - j; if (bt > 32) bt = 32;
    int e = csr[j + (l5 < bt ? l5 : bt - 1)];
    int tc = (bt + 1) >> 1;
    for (int t = 0; t < tc; ++t) {
      int p = 2 * t + slot;
      int a = __shfl(e, p);
      unsigned v = *(const unsigned*)(srcT + (size_t)(unsigned)a * H + l5 * 2);
      if (p >= bt) v = 0;
      union { unsigned u; float f; } lo, hi;
      lo.u = v << 16; hi.u = v & 0xffff0000u;
      ax += lo.f; ay += hi.f;
    }
  }
}

// ---------- merged fused SAGE layer-1 (MFMA transform) + classifier projection ----------
// Each 512-thread block = 8 waves, each wave 16 nodes. Gather mean in fp32 (dword loads,
// 4-node interleaved), split agg into bf16 hi+lo, MFMA vs bf16 weights, relu, project to
// 7+7 classifier dims, write Z row (16 bf16 slots; 7,15 zero).
__global__ __launch_bounds__(512, 4) void k_sage_mfma(
    const u16* __restrict__ xu, const u16* __restrict__ xm,
    const int* __restrict__ csr_u, const int* __restrict__ off_u,
    const int* __restrict__ csr_m, const int* __restrict__ off_m,
    const float* __restrict__ WlU, const float* __restrict__ blU, const float* __restrict__ WrU,
    const float* __restrict__ WlM, const float* __restrict__ blM, const float* __restrict__ WrM,
    const float* __restrict__ CWml, const float* __restrict__ CWur,   // user-side Z parts
    const float* __restrict__ CWul, const float* __restrict__ CWmr,   // movie-side Z parts
    u16* __restrict__ Zu, u16* __restrict__ Zm,
    int U_, int M_, int gU) {
  __shared__ int sWl[64 * 36];
  __shared__ int sWr[64 * 36];
  __shared__ int sAggHi[128 * 36];
  __shared__ int sAggLo[128 * 36];
  __shared__ float sCl[448];
  __shared__ float sCr[448];
  __shared__ float sBl[64];

  int movie = (blockIdx.x >= (unsigned)gU) ? 1 : 0;
  int bside = movie ? (blockIdx.x - gU) : blockIdx.x;
  const u16* srcT = movie ? xu : xm;
  const u16* rootT = movie ? xm : xu;
  const int* csr = movie ? csr_m : csr_u;
  const int* off = movie ? off_m : off_u;
  const float* Wl = movie ? WlM : WlU;
  const float* Wr = movie ? WrM : WrU;
  const float* bl = movie ? blM : blU;
  const float* CWl = movie ? CWul : CWml;
  const float* CWr = movie ? CWmr : CWur;
  u16* Z = movie ? Zm : Zu;
  int N = movie ? M_ : U_;

  int tid = threadIdx.x;
  // stage weights: W^T as bf16 pairs (row j, 32 dwords + 4 pad)
  for (int idx = tid; idx < 2048; idx += 512) {
    int j = idx & 63, kk = idx >> 6;   // kk = k-pair 0..31
    sWl[j * 36 + kk] = pack2bf(Wl[(2 * kk) * H + j], Wl[(2 * kk + 1) * H + j]);
    sWr[j * 36 + kk] = pack2bf(Wr[(2 * kk) * H + j], Wr[(2 * kk + 1) * H + j]);
  }
  for (int idx = tid; idx < 448; idx += 512) { sCl[idx] = CWl[idx]; sCr[idx] = CWr[idx]; }
  if (tid < 64) sBl[tid] = bl[tid];
  __syncthreads();

  int lane = tid & 63;
  int wid = tid >> 6;
  int slot = lane >> 5;
  int l5 = lane & 31;
  int node0 = bside * 128 + wid * 16;

  // ---- gather phase: 4 quads of 4 nodes, interleaved dword loads ----
  for (int g = 0; g < 4; ++g) {
    float ax[4], ay[4];
    int jb[4], en[4], d1[4], e[4];
    #pragma unroll
    for (int i = 0; i < 4; ++i) {
      int n = node0 + g * 4 + i;
      n = n < N ? n : N - 1;
      jb[i] = off[n]; en[i] = off[n + 1];
      int d = en[i] - jb[i];
      d1[i] = d > 32 ? 32 : d;
      e[i] = (d > 0) ? csr[jb[i] + (l5 < d1[i] ? l5 : d1[i] - 1)] : 0;
      ax[i] = 0.f; ay[i] = 0.f;
    }
    int dm = imax(imax(d1[0], d1[1]), imax(d1[2], d1[3]));
    int tc = (dm + 1) >> 1;
    #pragma unroll 2
    for (int t = 0; t < tc; ++t) {
      int p = 2 * t + slot;
      #pragma unroll
      for (int i = 0; i < 4; ++i) {
        int a = __shfl(e[i], p);
        unsigned v = *(const unsigned*)(srcT + (size_t)(unsigned)a * H + l5 * 2);
        if (p >= d1[i]) v = 0;
        union { unsigned u; float f; } lo, hi;
        lo.u = v << 16; hi.u = v & 0xffff0000u;
        ax[i] += lo.f; ay[i] += hi.f;
      }
    }
    #pragma unroll
    for (int i = 0; i < 4; ++i)
      if (en[i] - jb[i] > 32)
        gather_extra(srcT, csr, jb[i] + 32, en[i], l5, slot, ax[i], ay[i]);

    // finalize: combine half-waves, divide by degree, split hi/lo, store to LDS
    #pragma unroll
    for (int i = 0; i < 4; ++i) {
      float sx = ax[i] + __shfl_xor(ax[i], 32);
      float sy = ay[i] + __shfl_xor(ay[i], 32);
      float inv = 1.0f / (float)imax(en[i] - jb[i], 1);
      sx *= inv; sy *= inv;
      u16 bx = f2bf(sx), by = f2bf(sy);
      float rx = sx - bf2f(bx), ry = sy - bf2f(by);
      int hiw = (int)bx | ((int)by << 16);
      int low = (int)f2bf(rx) | ((int)f2bf(ry) << 16);
      int row = wid * 16 + g * 4 + i;
      if (slot == 0) sAggHi[row * 36 + l5] = hiw;
      else           sAggLo[row * 36 + l5] = low;
    }
  }
  // per-wave region: wave reads only its own writes; in-wave LDS ordering suffices

  // ---- MFMA transform phase ----
  int r16 = lane & 15;
  int q4 = lane >> 4;
  union FU { int4 i; bf16x8 b; };
  FU ahi[2], alo[2], art[2];
  int arow = wid * 16 + r16;
  int rnode = node0 + r16;
  rnode = rnode < N ? rnode : N - 1;
  #pragma unroll
  for (int kt = 0; kt < 2; ++kt) {
    ahi[kt].i = *(const int4*)&sAggHi[arow * 36 + kt * 16 + q4 * 4];
    alo[kt].i = *(const int4*)&sAggLo[arow * 36 + kt * 16 + q4 * 4];
    art[kt].i = ((const int4*)(rootT + (size_t)rnode * H))[kt * 4 + q4];
  }
  float val[4][4];
  #pragma unroll
  for (int t = 0; t < 4; ++t) {
    f32x4 cacc = {0.f, 0.f, 0.f, 0.f};
    #pragma unroll
    for (int kt = 0; kt < 2; ++kt) {
      FU bwl, bwr;
      bwl.i = *(const int4*)&sWl[(t * 16 + r16) * 36 + kt * 16 + q4 * 4];
      bwr.i = *(const int4*)&sWr[(t * 16 + r16) * 36 + kt * 16 + q4 * 4];
      cacc = __builtin_amdgcn_mfma_f32_16x16x32_bf16(ahi[kt].b, bwl.b, cacc, 0, 0, 0);
      cacc = __builtin_amdgcn_mfma_f32_16x16x32_bf16(alo[kt].b, bwl.b, cacc, 0, 0, 0);
      cacc = __builtin_amdgcn_mfma_f32_16x16x32_bf16(art[kt].b, bwr.b, cacc, 0, 0, 0);
    }
    float bj = sBl[t * 16 + r16];
    #pragma unroll
    for (int r = 0; r < 4; ++r) val[t][r] = fmaxf(cacc[r] + bj, 0.f);
  }

  // ---- classifier projection: Z[node][c] (c<7: @CWl), Z[node][8+c] (@CWr) ----
  float zacc[4] = {0.f, 0.f, 0.f, 0.f};
  #pragma unroll
  for (int c = 0; c < C; ++c) {
    float tl[4], tr[4];
    #pragma unroll
    for (int r = 0; r < 4; ++r) {
      tl[r] = val[0][r] * sCl[(r16) * C + c] + val[1][r] * sCl[(16 + r16) * C + c] +
              val[2][r] * sCl[(32 + r16) * C + c] + val[3][r] * sCl[(48 + r16) * C + c];
      tr[r] = val[0][r] * sCr[(r16) * C + c] + val[1][r] * sCr[(16 + r16) * C + c] +
              val[2][r] * sCr[(32 + r16) * C + c] + val[3][r] * sCr[(48 + r16) * C + c];
    }
    #pragma unroll
    for (int o = 1; o < 16; o <<= 1) {
      #pragma unroll
      for (int r = 0; r < 4; ++r) {
        tl[r] += __shfl_xor(tl[r], o);
        tr[r] += __shfl_xor(tr[r], o);
      }
    }
    #pragma unroll
    for (int r = 0; r < 4; ++r) {
      zacc[r] = (r16 == c) ? zacc[r] + tl[r] : zacc[r];
      zacc[r] = (r16 == 8 + c) ? zacc[r] + tr[r] : zacc[r];
    }
  }
  #pragma unroll
  for (int r = 0; r < 4; ++r) {
    int node = node0 + q4 * 4 + r;
    if (node < N) Z[(size_t)node * 16 + r16] = f2bf(zacc[r]);
  }
}

// ---------- merged layer-2 aggregation in projected bf16 space ----------
__global__ __launch_bounds__(256) void k_agg7m(
    const u16* __restrict__ Zu, const u16* __restrict__ Zm,
    const int* __restrict__ csr_u, const int* __restrict__ off_u,
    const int* __restrict__ csr_m, const int* __restrict__ off_m,
    const float* __restrict__ cbu, const float* __restrict__ cbm,
    float* __restrict__ Pu, float* __restrict__ Pm,
    int U_, int M_, int gU) {
  int movie = (blockIdx.x >= (unsigned)gU) ? 1 : 0;
  int bside = movie ? (blockIdx.x - gU) : blockIdx.x;
  const u16* Zsrc = movie ? Zu : Zm;
  const u16* Zroot = movie ? Zm : Zu;
  const int* csr = movie ? csr_m : csr_u;
  const int* off = movie ? off_m : off_u;
  const float* cb = movie ? cbm : cbu;
  float* P = movie ? Pm : Pu;
  int N = movie ? M_ : U_;

  int n = bside * 256 + threadIdx.x;
  if (n >= N) return;
  int beg = off[n], end = off[n + 1];
  float acc[8] = {0.f, 0.f, 0.f, 0.f, 0.f, 0.f, 0.f, 0.f};
  for (int j = beg; j < end; ++j) {
    int a = csr[j];
    ushort4 z0 = *(const ushort4*)(Zsrc + (size_t)a * 16);
    ushort4 z1 = *(const ushort4*)(Zsrc + (size_t)a * 16 + 4);
    acc[0] += bf2f(z0.x); acc[1] += bf2f(z0.y); acc[2] += bf2f(z0.z); acc[3] += bf2f(z0.w);
    acc[4] += bf2f(z1.x); acc[5] += bf2f(z1.y); acc[6] += bf2f(z1.z); acc[7] += bf2f(z1.w);
  }
  float inv = 1.f / (float)imax(end - beg, 1);
  ushort4 r0 = *(const ushort4*)(Zroot + (size_t)n * 16 + 8);
  ushort4 r1 = *(const ushort4*)(Zroot + (size_t)n * 16 + 12);
  float4 o0, o1;
  o0.x = acc[0] * inv + bf2f(r0.x) + cb[0];
  o0.y = acc[1] * inv + bf2f(r0.y) + cb[1];
  o0.z = acc[2] * inv + bf2f(r0.z) + cb[2];
  o0.w = acc[3] * inv + bf2f(r0.w) + cb[3];
  o1.x = acc[4] * inv + bf2f(r1.x) + cb[4];
  o1.y = acc[5] * inv + bf2f(r1.y) + cb[5];
  o1.z = acc[6] * inv + bf2f(r1.z) + cb[6];
  o1.w = 0.f;
  float4* po = (float4*)(P + (size_t)n * 8);
  po[0] = o0;
  po[1] = o1;
}

// ---------- final edge classifier ----------
__global__ void k_final(const int* __restrict__ els, const int* __restrict__ eld,
                        const float* __restrict__ Pu, const float* __restrict__ Pm,
                        const float* __restrict__ clsb, float* __restrict__ out, int total) {
  int t = blockIdx.x * 256 + threadIdx.x;
  if (t >= total) return;
  int e = t / C, c = t - e * C;
  out[t] = Pu[(size_t)els[e] * 8 + c] + Pm[(size_t)eld[e] * 8 + c] + clsb[c];
}

extern "C" void kernel_launch(void* const* d_in, const int* in_sizes, int n_in,
                              void* d_out, int out_size, void* d_ws, size_t ws_size,
                              hipStream_t stream) {
  (void)n_in; (void)out_size; (void)ws_size;
  const int*   unid      = (const int*)d_in[0];
  const int*   mnid      = (const int*)d_in[1];
  const float* movie_x   = (const float*)d_in[2];
  const int*   e_src     = (const int*)d_in[3];
  const int*   e_dst     = (const int*)d_in[4];
  const int*   el_src    = (const int*)d_in[5];
  const int*   el_dst    = (const int*)d_in[6];
  const float* user_emb  = (const float*)d_in[7];
  const float* movie_emb = (const float*)d_in[8];
  const float* w_movie   = (const float*)d_in[9];
  const float* b_movie   = (const float*)d_in[10];
  const float* l1r_Wl    = (const float*)d_in[11];
  const float* l1r_bl    = (const float*)d_in[12];
  const float* l1r_Wr    = (const float*)d_in[13];
  const float* l1v_Wl    = (const float*)d_in[14];
  const float* l1v_bl    = (const float*)d_in[15];
  const float* l1v_Wr    = (const float*)d_in[16];
  const float* l2r_Wl    = (const float*)d_in[17];
  const float* l2r_bl    = (const float*)d_in[18];
  const float* l2r_Wr    = (const float*)d_in[19];
  const float* l2v_Wl    = (const float*)d_in[20];
  const float* l2v_bl    = (const float*)d_in[21];
  const float* l2v_Wr    = (const float*)d_in[22];
  const float* cls_W     = (const float*)d_in[23];
  const float* cls_b     = (const float*)d_in[24];

  int U  = in_sizes[0];
  int M  = in_sizes[1];
  int E  = in_sizes[3];
  int EL = in_sizes[5];

  int nbu = (U + BSZ - 1) / BSZ;
  int nbm = (M + BSZ - 1) / BSZ;
  int nchunks = (E + CH - 1) / CH;

  char* p = (char*)d_ws;
  auto alloc = [&](size_t nbytes) { char* r = p; p += (nbytes + 255) & ~(size_t)255; return r; };

  u16*   xm_bf  = (u16*)alloc((size_t)M * H * 2);
  u16*   xu_bf  = (u16*)alloc((size_t)U * H * 2);
  u16*   Zu     = (u16*)alloc((size_t)U * 16 * 2);
  u16*   Zm     = (u16*)alloc((size_t)M * 16 * 2);
  float* Pu     = (float*)alloc((size_t)U * 8 * 4);
  float* Pm     = (float*)alloc((size_t)M * 8 * 4);
  int*   csr_u  = (int*)alloc((size_t)E * 4);
  int*   csr_m  = (int*)alloc((size_t)E * 4);
  int*   off_u  = (int*)alloc((size_t)(U + 1) * 4);
  int*   off_m  = (int*)alloc((size_t)(M + 1) * 4);
  unsigned int* pk_u = (unsigned int*)alloc((size_t)E * 4);
  unsigned int* pk_m = (unsigned int*)alloc((size_t)E * 4);
  int*   gcnt   = (int*)alloc((size_t)(nbu + nbm) * 4);
  int*   gcnt_u = gcnt;
  int*   gcnt_m = gcnt + nbu;
  int*   boff_u = (int*)alloc((size_t)(nbu + 1) * 4);
  int*   boff_m = (int*)alloc((size_t)(nbm + 1) * 4);
  int*   gcur_u = (int*)alloc((size_t)nbu * 4);
  int*   gcur_m = (int*)alloc((size_t)nbm * 4);
  float* cw     = (float*)alloc(1806 * 4);
  float* CWul = cw, *CWur = cw + 448, *CWml = cw + 896, *CWmr = cw + 1344;
  float* cbu  = cw + 1792, *cbm = cw + 1799;

  hipMemsetAsync(gcnt, 0, (size_t)(nbu + nbm) * 4, stream);

  // ---- CSR build ----
  k_bhist<<<256, 256, (size_t)(nbu + nbm) * 4, stream>>>(e_src, e_dst, E, gcnt_u, gcnt_m, nbu, nbm);
  k_bscan<<<1, 256, 0, stream>>>(gcnt_u, gcnt_m, nbu, nbm, E, boff_u, boff_m, gcur_u, gcur_m);
  k_bscat<<<2 * nchunks, 256, (size_t)(2 * nbu) * 4, stream>>>(e_src, e_dst, E, gcur_u, gcur_m,
                                                               pk_u, pk_m, nbu, nbm, nchunks);
  k_bbuild<<<nbu + nbm, 512, 0, stream>>>(pk_u, pk_m, boff_u, boff_m, nbu, nbm, U, M, E,
                                          csr_u, csr_m, off_u, off_m);

  // ---- feature tables (bf16) + combined classifier weights ----
  k_proj<<<(M * H + 255) / 256, 256, 0, stream>>>(movie_x, w_movie, b_movie, movie_emb, mnid, xm_bf, M);
  k_cvtu<<<(U * 16 + 255) / 256, 256, 0, stream>>>(user_emb, unid, xu_bf, U);
  k_cw<<<8, 256, 0, stream>>>(l2v_Wl, l2v_Wr, l2v_bl, l2r_Wl, l2r_Wr, l2r_bl, cls_W, cw);

  // ---- merged layer-1 (MFMA) fused with classifier projection ----
  int gU_s = (U + 127) / 128;
  int gM_s = (M + 127) / 128;
  k_sage_mfma<<<gU_s + gM_s, 512, 0, stream>>>(
      xu_bf, xm_bf, csr_u, off_u, csr_m, off_m,
      l1v_Wl, l1v_bl, l1v_Wr,          // user-side layer-1 weights (rev)
      l1r_Wl, l1r_bl, l1r_Wr,          // movie-side layer-1 weights (rates)
      CWml, CWur, CWul, CWmr,
      Zu, Zm, U, M, gU_s);

  // ---- merged layer-2 aggregation ----
  int gU_a = (U + 255) / 256;
  int gM_a = (M + 255) / 256;
  k_agg7m<<<gU_a + gM_a, 256, 0, stream>>>(Zu, Zm, csr_u, off_u, csr_m, off_m,
                                           cbu, cbm, Pu, Pm, U, M, gU_a);

  // ---- final ----
  int total = EL * C;
  k_final<<<(total + 255) / 256, 256, 0, stream>>>(el_src, el_dst, Pu, Pm, cls_b, (float*)d_out, total);
}

// Round 5
// 524.555 us; speedup vs baseline: 3.0757x; 1.1621x over previous
//
#include <hip/hip_runtime.h>
#include <cstdint>
#include <cstddef>

#define H 64
#define C 7
#define F 20
#define BSH 9
#define BSZ 512
#define CH 8192

typedef unsigned short u16;
typedef __attribute__((ext_vector_type(8))) short bf16x8;
typedef __attribute__((ext_vector_type(4))) float f32x4;

static __device__ __forceinline__ int imax(int a, int b) { return a > b ? a : b; }
static __device__ __forceinline__ int imin(int a, int b) { return a < b ? a : b; }

static __device__ __forceinline__ float bf2f(u16 v) {
  union { unsigned u; float f; } x; x.u = ((unsigned)v) << 16; return x.f;
}
static __device__ __forceinline__ u16 f2bf(float f) {  // round-nearest-even
  union { float f; unsigned u; } x; x.f = f;
  unsigned r = x.u + 0x7fffu + ((x.u >> 16) & 1u);
  return (u16)(r >> 16);
}
static __device__ __forceinline__ int pack2bf(float a, float b) {
  return (int)f2bf(a) | ((int)f2bf(b) << 16);
}
static __device__ __forceinline__ float lo16f(unsigned v) {
  union { unsigned u; float f; } x; x.u = v << 16; return x.f;
}
static __device__ __forceinline__ float hi16f(unsigned v) {
  union { unsigned u; float f; } x; x.u = v & 0xffff0000u; return x.f;
}

// ---------- phase 1: coarse bucket histogram ----------
__global__ __launch_bounds__(256) void k_bhist(const int* __restrict__ esrc,
                                               const int* __restrict__ edst, int E,
                                               int* __restrict__ gcnt_u, int* __restrict__ gcnt_m,
                                               int nbu, int nbm) {
  extern __shared__ int sh[];
  int* hu = sh;
  int* hm = sh + nbu;
  for (int i = threadIdx.x; i < nbu + nbm; i += 256) sh[i] = 0;
  __syncthreads();
  int stride = gridDim.x * 256;
  for (int i = blockIdx.x * 256 + threadIdx.x; i < E; i += stride) {
    atomicAdd(&hu[esrc[i] >> BSH], 1);
    atomicAdd(&hm[edst[i] >> BSH], 1);
  }
  __syncthreads();
  for (int i = threadIdx.x; i < nbu; i += 256) if (hu[i]) atomicAdd(&gcnt_u[i], hu[i]);
  for (int i = threadIdx.x; i < nbm; i += 256) if (hm[i]) atomicAdd(&gcnt_m[i], hm[i]);
}

// ---------- phase 2: scan bucket counts ----------
__global__ __launch_bounds__(256) void k_bscan(const int* __restrict__ gcnt_u,
                                               const int* __restrict__ gcnt_m,
                                               int nbu, int nbm, int E,
                                               int* __restrict__ boff_u, int* __restrict__ boff_m,
                                               int* __restrict__ gcur_u, int* __restrict__ gcur_m) {
  __shared__ int s[1024];
  for (int i = threadIdx.x; i < nbu; i += 256) s[i] = gcnt_u[i];
  for (int i = threadIdx.x; i < nbm; i += 256) s[512 + i] = gcnt_m[i];
  __syncthreads();
  if (threadIdx.x == 0) {
    int r = 0;
    for (int i = 0; i < nbu; ++i) { int v = s[i]; s[i] = r; r += v; }
  }
  if (threadIdx.x == 1) {
    int r = 0;
    for (int i = 0; i < nbm; ++i) { int v = s[512 + i]; s[512 + i] = r; r += v; }
  }
  __syncthreads();
  for (int i = threadIdx.x; i < nbu; i += 256) { boff_u[i] = s[i]; gcur_u[i] = s[i]; }
  for (int i = threadIdx.x; i < nbm; i += 256) { boff_m[i] = s[512 + i]; gcur_m[i] = s[512 + i]; }
  if (threadIdx.x == 0) { boff_u[nbu] = E; boff_m[nbm] = E; }
}

// ---------- phase 3: binning scatter into coarse buckets ----------
__global__ __launch_bounds__(256) void k_bscat(const int* __restrict__ esrc,
                                               const int* __restrict__ edst, int E,
                                               int* __restrict__ gcur_u, int* __restrict__ gcur_m,
                                               unsigned int* __restrict__ pk_u,
                                               unsigned int* __restrict__ pk_m,
                                               int nbu, int nbm, int nchunks) {
  extern __shared__ int sh2[];
  int dir = (blockIdx.x >= (unsigned)nchunks) ? 1 : 0;
  int chunk = dir ? (blockIdx.x - nchunks) : blockIdx.x;
  const int* key = dir ? edst : esrc;
  const int* pay = dir ? esrc : edst;
  int* gcur = dir ? gcur_m : gcur_u;
  unsigned int* pk = dir ? pk_m : pk_u;
  int nb = dir ? nbm : nbu;
  int* cnt = sh2;
  int* base = sh2 + nb;
  int beg = chunk * CH;
  int end = imin(beg + CH, E);
  for (int i = threadIdx.x; i < nb; i += 256) cnt[i] = 0;
  __syncthreads();
  for (int i = beg + threadIdx.x; i < end; i += 256) atomicAdd(&cnt[key[i] >> BSH], 1);
  __syncthreads();
  for (int i = threadIdx.x; i < nb; i += 256) {
    int c = cnt[i];
    base[i] = c ? atomicAdd(&gcur[i], c) : 0;
    cnt[i] = 0;
  }
  __syncthreads();
  for (int i = beg + threadIdx.x; i < end; i += 256) {
    int k = key[i];
    int b = k >> BSH;
    int r = atomicAdd(&cnt[b], 1);
    pk[base[b] + r] = ((unsigned)(k & (BSZ - 1)) << 18) | (unsigned)pay[i];
  }
}

// ---------- phase 4: per-bucket CSR build ----------
__global__ __launch_bounds__(512) void k_bbuild(const unsigned int* __restrict__ pk_u,
                                                const unsigned int* __restrict__ pk_m,
                                                const int* __restrict__ boff_u,
                                                const int* __restrict__ boff_m,
                                                int nbu, int nbm, int U_, int M_, int E,
                                                int* __restrict__ csr_u, int* __restrict__ csr_m,
                                                int* __restrict__ off_u, int* __restrict__ off_m) {
  __shared__ int hist[BSZ];
  __shared__ int cur[BSZ];
  int dir = (blockIdx.x >= (unsigned)nbu) ? 1 : 0;
  int b = dir ? (blockIdx.x - nbu) : blockIdx.x;
  const unsigned int* pk = dir ? pk_m : pk_u;
  const int* boff = dir ? boff_m : boff_u;
  int N = dir ? M_ : U_;
  int nb = dir ? nbm : nbu;
  int* csr = dir ? csr_m : csr_u;
  int* off = dir ? off_m : off_u;
  int beg = boff[b], end = boff[b + 1];
  int t = threadIdx.x;
  hist[t] = 0;
  __syncthreads();
  for (int i = beg + t; i < end; i += 512) atomicAdd(&hist[pk[i] >> 18], 1);
  __syncthreads();
  int v0 = hist[t];
  for (int o = 1; o < 512; o <<= 1) {
    int x = (t >= o) ? hist[t - o] : 0;
    __syncthreads();
    hist[t] += x;
    __syncthreads();
  }
  int excl = hist[t] - v0;
  cur[t] = excl;
  int node = (b << BSH) + t;
  if (node < N) off[node] = beg + excl;
  if (t == 0 && b == nb - 1) off[N] = E;
  __syncthreads();
  for (int i = beg + t; i < end; i += 512) {
    unsigned int p = pk[i];
    int n = (int)(p >> 18);
    int r = atomicAdd(&cur[n], 1);
    csr[beg + r] = (int)(p & 0x3FFFFu);
  }
}

// ---------- merged prep: movie projection + user cvt + combined classifier weights ----------
__global__ __launch_bounds__(256) void k_prep(
    const float* __restrict__ movie_x, const float* __restrict__ w_movie,
    const float* __restrict__ b_movie, const float* __restrict__ movie_emb,
    const int* __restrict__ mnid,
    const float* __restrict__ user_emb, const int* __restrict__ unid,
    const float* __restrict__ l2u_Wl, const float* __restrict__ l2u_Wr,
    const float* __restrict__ l2u_bl,
    const float* __restrict__ l2m_Wl, const float* __restrict__ l2m_Wr,
    const float* __restrict__ l2m_bl,
    const float* __restrict__ clsW,
    u16* __restrict__ xm_bf, u16* __restrict__ xu_bf, float* __restrict__ cw,
    int M_, int U_, int gProj, int gCvt) {
  __shared__ float ws_[F * H];
  int b = blockIdx.x;
  if (b < gProj) {
    for (int i = threadIdx.x; i < F * H; i += 256) ws_[i] = w_movie[i];
    __syncthreads();
    int t = b * 256 + threadIdx.x;
    int m = t >> 6;
    int h = t & 63;
    if (m >= M_) return;
    float acc = b_movie[h] + movie_emb[(size_t)mnid[m] * H + h];
    const float* xr = movie_x + (size_t)m * F;
    #pragma unroll
    for (int f = 0; f < F; ++f) acc += xr[f] * ws_[f * H + h];
    xm_bf[(size_t)m * H + h] = f2bf(acc);
  } else if (b < gProj + gCvt) {
    int t = (b - gProj) * 256 + threadIdx.x;
    if (t >= U_ * 16) return;
    int i = t >> 4;
    int g = t & 15;
    const float4 v = *(const float4*)(user_emb + (size_t)unid[i] * H + g * 4);
    ushort4 o;
    o.x = f2bf(v.x); o.y = f2bf(v.y); o.z = f2bf(v.z); o.w = f2bf(v.w);
    *(ushort4*)(xu_bf + (size_t)i * H + g * 4) = o;
  } else {
    int t = (b - gProj - gCvt) * 256 + threadIdx.x;
    if (t < 448) {
      int k = t / C, c = t % C;
      float s = 0.f;
      for (int j = 0; j < H; ++j) s += l2u_Wl[k * H + j] * clsW[j * C + c];
      cw[t] = s;
    } else if (t < 896) {
      int u = t - 448; int k = u / C, c = u % C;
      float s = 0.f;
      for (int j = 0; j < H; ++j) s += l2u_Wr[k * H + j] * clsW[j * C + c];
      cw[t] = s;
    } else if (t < 1344) {
      int u = t - 896; int k = u / C, c = u % C;
      float s = 0.f;
      for (int j = 0; j < H; ++j) s += l2m_Wl[k * H + j] * clsW[(H + j) * C + c];
      cw[t] = s;
    } else if (t < 1792) {
      int u = t - 1344; int k = u / C, c = u % C;
      float s = 0.f;
      for (int j = 0; j < H; ++j) s += l2m_Wr[k * H + j] * clsW[(H + j) * C + c];
      cw[t] = s;
    } else if (t < 1799) {
      int c = t - 1792;
      float s = 0.f;
      for (int j = 0; j < H; ++j) s += l2u_bl[j] * clsW[j * C + c];
      cw[t] = s;
    } else if (t < 1806) {
      int c = t - 1799;
      float s = 0.f;
      for (int j = 0; j < H; ++j) s += l2m_bl[j] * clsW[(H + j) * C + c];
      cw[t] = s;
    }
  }
}

// ---------- merged fused SAGE layer-1 (MFMA transform) + classifier projection ----------
// Gather: 8 slots/wave, slot owns one node; lane l3 (0..7) loads dwordx4 (8 bf16 cols)
// of each neighbor row -> one wave-level load instr covers 8 full rows; each lane
// accumulates its 8 columns in fp32 over all its node's neighbors (no cross-lane
// reduction). Then mean, bf16 hi+lo split, MFMA vs bf16 weights, relu, project to
// 7+7 classifier dims, write Z row (bf16).
__global__ __launch_bounds__(512, 4) void k_sage_mfma(
    const u16* __restrict__ xu, const u16* __restrict__ xm,
    const int* __restrict__ csr_u, const int* __restrict__ off_u,
    const int* __restrict__ csr_m, const int* __restrict__ off_m,
    const float* __restrict__ WlU, const float* __restrict__ blU, const float* __restrict__ WrU,
    const float* __restrict__ WlM, const float* __restrict__ blM, const float* __restrict__ WrM,
    const float* __restrict__ CWml, const float* __restrict__ CWur,   // user-side Z parts
    const float* __restrict__ CWul, const float* __restrict__ CWmr,   // movie-side Z parts
    u16* __restrict__ Zu, u16* __restrict__ Zm,
    int U_, int M_, int E_, int gU) {
  __shared__ int sWl[64 * 36];
  __shared__ int sWr[64 * 36];
  __shared__ int sAggHi[128 * 36];
  __shared__ int sAggLo[128 * 36];
  __shared__ float sCl[448];
  __shared__ float sCr[448];
  __shared__ float sBl[64];

  int movie = (blockIdx.x >= (unsigned)gU) ? 1 : 0;
  int bside = movie ? (blockIdx.x - gU) : blockIdx.x;
  const u16* srcT = movie ? xu : xm;
  const u16* rootT = movie ? xm : xu;
  const int* csr = movie ? csr_m : csr_u;
  const int* off = movie ? off_m : off_u;
  const float* Wl = movie ? WlM : WlU;
  const float* Wr = movie ? WrM : WrU;
  const float* bl = movie ? blM : blU;
  const float* CWl = movie ? CWul : CWml;
  const float* CWr = movie ? CWmr : CWur;
  u16* Z = movie ? Zm : Zu;
  int N = movie ? M_ : U_;

  int tid = threadIdx.x;
  // stage weights: W^T as bf16 pairs (row j, 32 dwords + 4 pad)
  for (int idx = tid; idx < 2048; idx += 512) {
    int j = idx & 63, kk = idx >> 6;
    sWl[j * 36 + kk] = pack2bf(Wl[(2 * kk) * H + j], Wl[(2 * kk + 1) * H + j]);
    sWr[j * 36 + kk] = pack2bf(Wr[(2 * kk) * H + j], Wr[(2 * kk + 1) * H + j]);
  }
  for (int idx = tid; idx < 448; idx += 512) { sCl[idx] = CWl[idx]; sCr[idx] = CWr[idx]; }
  if (tid < 64) sBl[tid] = bl[tid];
  __syncthreads();

  int lane = tid & 63;
  int wid = tid >> 6;
  int slot = lane >> 3;      // 0..7: node within group
  int l3 = lane & 7;         // 0..7: column-octet within row
  int sbase = slot * 8;
  int node0 = bside * 128 + wid * 16;

  // ---- gather phase: 2 groups of 8 nodes; per-node-slot dwordx4 accumulation ----
  #pragma unroll
  for (int g = 0; g < 2; ++g) {
    int n = node0 + g * 8 + slot;
    int nc = n < N ? n : N - 1;
    int jb = off[nc];
    int d = off[nc + 1] - jb;
    if (n >= N) d = 0;
    int dm1 = imax(d - 1, 0);
    int dmax = d;
    dmax = imax(dmax, __shfl_xor(dmax, 8));
    dmax = imax(dmax, __shfl_xor(dmax, 16));
    dmax = imax(dmax, __shfl_xor(dmax, 32));

    float acc[8] = {0.f, 0.f, 0.f, 0.f, 0.f, 0.f, 0.f, 0.f};
    for (int tb = 0; tb < dmax; tb += 8) {
      int ci = jb + imin(tb + l3, dm1);
      ci = imin(ci, E_ - 1);
      int e = csr[ci];                    // neighbors tb..tb+7 of this slot's node
      uint4 v[8];
      #pragma unroll
      for (int k = 0; k < 8; ++k) {
        int a = __shfl(e, sbase + k);
        v[k] = *(const uint4*)(srcT + (size_t)(unsigned)a * H + l3 * 8);
      }
      #pragma unroll
      for (int k = 0; k < 8; ++k) {
        float mk = (tb + k < d) ? 1.0f : 0.0f;
        acc[0] = fmaf(lo16f(v[k].x), mk, acc[0]);
        acc[1] = fmaf(hi16f(v[k].x), mk, acc[1]);
        acc[2] = fmaf(lo16f(v[k].y), mk, acc[2]);
        acc[3] = fmaf(hi16f(v[k].y), mk, acc[3]);
        acc[4] = fmaf(lo16f(v[k].z), mk, acc[4]);
        acc[5] = fmaf(hi16f(v[k].z), mk, acc[5]);
        acc[6] = fmaf(lo16f(v[k].w), mk, acc[6]);
        acc[7] = fmaf(hi16f(v[k].w), mk, acc[7]);
      }
    }

    // finalize: mean, hi/lo bf16 split, b128 LDS store
    float inv = 1.0f / (float)imax(d, 1);
    int hi4[4], lo4[4];
    #pragma unroll
    for (int pp = 0; pp < 4; ++pp) {
      float s0 = acc[2 * pp] * inv;
      float s1 = acc[2 * pp + 1] * inv;
      u16 b0 = f2bf(s0), b1 = f2bf(s1);
      float r0 = s0 - bf2f(b0), r1 = s1 - bf2f(b1);
      hi4[pp] = (int)b0 | ((int)b1 << 16);
      lo4[pp] = pack2bf(r0, r1);
    }
    int row = wid * 16 + g * 8 + slot;
    *(int4*)&sAggHi[row * 36 + l3 * 4] = *(int4*)hi4;
    *(int4*)&sAggLo[row * 36 + l3 * 4] = *(int4*)lo4;
  }
  // per-wave region: wave reads only its own writes; in-wave LDS ordering suffices

  // ---- MFMA transform phase ----
  int r16 = lane & 15;
  int q4 = lane >> 4;
  union FU { int4 i; bf16x8 b; };
  FU ahi[2], alo[2], art[2];
  int arow = wid * 16 + r16;
  int rnode = node0 + r16;
  rnode = rnode < N ? rnode : N - 1;
  #pragma unroll
  for (int kt = 0; kt < 2; ++kt) {
    ahi[kt].i = *(const int4*)&sAggHi[arow * 36 + kt * 16 + q4 * 4];
    alo[kt].i = *(const int4*)&sAggLo[arow * 36 + kt * 16 + q4 * 4];
    art[kt].i = ((const int4*)(rootT + (size_t)rnode * H))[kt * 4 + q4];
  }
  float val[4][4];
  #pragma unroll
  for (int t = 0; t < 4; ++t) {
    f32x4 cacc = {0.f, 0.f, 0.f, 0.f};
    #pragma unroll
    for (int kt = 0; kt < 2; ++kt) {
      FU bwl, bwr;
      bwl.i = *(const int4*)&sWl[(t * 16 + r16) * 36 + kt * 16 + q4 * 4];
      bwr.i = *(const int4*)&sWr[(t * 16 + r16) * 36 + kt * 16 + q4 * 4];
      cacc = __builtin_amdgcn_mfma_f32_16x16x32_bf16(ahi[kt].b, bwl.b, cacc, 0, 0, 0);
      cacc = __builtin_amdgcn_mfma_f32_16x16x32_bf16(alo[kt].b, bwl.b, cacc, 0, 0, 0);
      cacc = __builtin_amdgcn_mfma_f32_16x16x32_bf16(art[kt].b, bwr.b, cacc, 0, 0, 0);
    }
    float bj = sBl[t * 16 + r16];
    #pragma unroll
    for (int r = 0; r < 4; ++r) val[t][r] = fmaxf(cacc[r] + bj, 0.f);
  }

  // ---- classifier projection: Z[node][c] (c<7: @CWl), Z[node][8+c] (@CWr) ----
  float zacc[4] = {0.f, 0.f, 0.f, 0.f};
  #pragma unroll
  for (int c = 0; c < C; ++c) {
    float tl[4], tr[4];
    #pragma unroll
    for (int r = 0; r < 4; ++r) {
      tl[r] = val[0][r] * sCl[(r16) * C + c] + val[1][r] * sCl[(16 + r16) * C + c] +
              val[2][r] * sCl[(32 + r16) * C + c] + val[3][r] * sCl[(48 + r16) * C + c];
      tr[r] = val[0][r] * sCr[(r16) * C + c] + val[1][r] * sCr[(16 + r16) * C + c] +
              val[2][r] * sCr[(32 + r16) * C + c] + val[3][r] * sCr[(48 + r16) * C + c];
    }
    #pragma unroll
    for (int o = 1; o < 16; o <<= 1) {
      #pragma unroll
      for (int r = 0; r < 4; ++r) {
        tl[r] += __shfl_xor(tl[r], o);
        tr[r] += __shfl_xor(tr[r], o);
      }
    }
    #pragma unroll
    for (int r = 0; r < 4; ++r) {
      zacc[r] = (r16 == c) ? zacc[r] + tl[r] : zacc[r];
      zacc[r] = (r16 == 8 + c) ? zacc[r] + tr[r] : zacc[r];
    }
  }
  #pragma unroll
  for (int r = 0; r < 4; ++r) {
    int node = node0 + q4 * 4 + r;
    if (node < N) Z[(size_t)node * 16 + r16] = f2bf(zacc[r]);
  }
}

// ---------- merged layer-2 aggregation in projected bf16 space ----------
__global__ __launch_bounds__(256) void k_agg7m(
    const u16* __restrict__ Zu, const u16* __restrict__ Zm,
    const int* __restrict__ csr_u, const int* __restrict__ off_u,
    const int* __restrict__ csr_m, const int* __restrict__ off_m,
    const float* __restrict__ cbu, const float* __restrict__ cbm,
    float* __restrict__ Pu, float* __restrict__ Pm,
    int U_, int M_, int gU) {
  int movie = (blockIdx.x >= (unsigned)gU) ? 1 : 0;
  int bside = movie ? (blockIdx.x - gU) : blockIdx.x;
  const u16* Zsrc = movie ? Zu : Zm;
  const u16* Zroot = movie ? Zm : Zu;
  const int* csr = movie ? csr_m : csr_u;
  const int* off = movie ? off_m : off_u;
  const float* cb = movie ? cbm : cbu;
  float* P = movie ? Pm : Pu;
  int N = movie ? M_ : U_;

  int n = bside * 256 + threadIdx.x;
  if (n >= N) return;
  int beg = off[n], end = off[n + 1];
  float acc[8] = {0.f, 0.f, 0.f, 0.f, 0.f, 0.f, 0.f, 0.f};
  for (int j = beg; j < end; ++j) {
    int a = csr[j];
    uint4 z = *(const uint4*)(Zsrc + (size_t)a * 16);
    acc[0] += lo16f(z.x); acc[1] += hi16f(z.x);
    acc[2] += lo16f(z.y); acc[3] += hi16f(z.y);
    acc[4] += lo16f(z.z); acc[5] += hi16f(z.z);
    acc[6] += lo16f(z.w); acc[7] += hi16f(z.w);
  }
  float inv = 1.f / (float)imax(end - beg, 1);
  uint4 zr = *(const uint4*)(Zroot + (size_t)n * 16 + 8);
  float4 o0, o1;
  o0.x = acc[0] * inv + lo16f(zr.x) + cb[0];
  o0.y = acc[1] * inv + hi16f(zr.x) + cb[1];
  o0.z = acc[2] * inv + lo16f(zr.y) + cb[2];
  o0.w = acc[3] * inv + hi16f(zr.y) + cb[3];
  o1.x = acc[4] * inv + lo16f(zr.z) + cb[4];
  o1.y = acc[5] * inv + hi16f(zr.z) + cb[5];
  o1.z = acc[6] * inv + lo16f(zr.w) + cb[6];
  o1.w = 0.f;
  float4* po = (float4*)(P + (size_t)n * 8);
  po[0] = o0;
  po[1] = o1;
}

// ---------- final edge classifier ----------
__global__ void k_final(const int* __restrict__ els, const int* __restrict__ eld,
                        const float* __restrict__ Pu, const float* __restrict__ Pm,
                        const float* __restrict__ clsb, float* __restrict__ out, int total) {
  int t = blockIdx.x * 256 + threadIdx.x;
  if (t >= total) return;
  int e = t / C, c = t - e * C;
  out[t] = Pu[(size_t)els[e] * 8 + c] + Pm[(size_t)eld[e] * 8 + c] + clsb[c];
}

extern "C" void kernel_launch(void* const* d_in, const int* in_sizes, int n_in,
                              void* d_out, int out_size, void* d_ws, size_t ws_size,
                              hipStream_t stream) {
  (void)n_in; (void)out_size; (void)ws_size;
  const int*   unid      = (const int*)d_in[0];
  const int*   mnid      = (const int*)d_in[1];
  const float* movie_x   = (const float*)d_in[2];
  const int*   e_src     = (const int*)d_in[3];
  const int*   e_dst     = (const int*)d_in[4];
  const int*   el_src    = (const int*)d_in[5];
  const int*   el_dst    = (const int*)d_in[6];
  const float* user_emb  = (const float*)d_in[7];
  const float* movie_emb = (const float*)d_in[8];
  const float* w_movie   = (const float*)d_in[9];
  const float* b_movie   = (const float*)d_in[10];
  const float* l1r_Wl    = (const float*)d_in[11];
  const float* l1r_bl    = (const float*)d_in[12];
  const float* l1r_Wr    = (const float*)d_in[13];
  const float* l1v_Wl    = (const float*)d_in[14];
  const float* l1v_bl    = (const float*)d_in[15];
  const float* l1v_Wr    = (const float*)d_in[16];
  const float* l2r_Wl    = (const float*)d_in[17];
  const float* l2r_bl    = (const float*)d_in[18];
  const float* l2r_Wr    = (const float*)d_in[19];
  const float* l2v_Wl    = (const float*)d_in[20];
  const float* l2v_bl    = (const float*)d_in[21];
  const float* l2v_Wr    = (const float*)d_in[22];
  const float* cls_W     = (const float*)d_in[23];
  const float* cls_b     = (const float*)d_in[24];

  int U  = in_sizes[0];
  int M  = in_sizes[1];
  int E  = in_sizes[3];
  int EL = in_sizes[5];

  int nbu = (U + BSZ - 1) / BSZ;
  int nbm = (M + BSZ - 1) / BSZ;
  int nchunks = (E + CH - 1) / CH;

  char* p = (char*)d_ws;
  auto alloc = [&](size_t nbytes) { char* r = p; p += (nbytes + 255) & ~(size_t)255; return r; };

  u16*   xm_bf  = (u16*)alloc((size_t)M * H * 2);
  u16*   xu_bf  = (u16*)alloc((size_t)U * H * 2);
  u16*   Zu     = (u16*)alloc((size_t)U * 16 * 2);
  u16*   Zm     = (u16*)alloc((size_t)M * 16 * 2);
  float* Pu     = (float*)alloc((size_t)U * 8 * 4);
  float* Pm     = (float*)alloc((size_t)M * 8 * 4);
  int*   csr_u  = (int*)alloc((size_t)E * 4);
  int*   csr_m  = (int*)alloc((size_t)E * 4);
  int*   off_u  = (int*)alloc((size_t)(U + 1) * 4);
  int*   off_m  = (int*)alloc((size_t)(M + 1) * 4);
  unsigned int* pk_u = (unsigned int*)alloc((size_t)E * 4);
  unsigned int* pk_m = (unsigned int*)alloc((size_t)E * 4);
  int*   gcnt   = (int*)alloc((size_t)(nbu + nbm) * 4);
  int*   gcnt_u = gcnt;
  int*   gcnt_m = gcnt + nbu;
  int*   boff_u = (int*)alloc((size_t)(nbu + 1) * 4);
  int*   boff_m = (int*)alloc((size_t)(nbm + 1) * 4);
  int*   gcur_u = (int*)alloc((size_t)nbu * 4);
  int*   gcur_m = (int*)alloc((size_t)nbm * 4);
  float* cw     = (float*)alloc(1806 * 4);
  float* CWul = cw, *CWur = cw + 448, *CWml = cw + 896, *CWmr = cw + 1344;
  float* cbu  = cw + 1792, *cbm = cw + 1799;

  hipMemsetAsync(gcnt, 0, (size_t)(nbu + nbm) * 4, stream);

  // ---- CSR build ----
  k_bhist<<<256, 256, (size_t)(nbu + nbm) * 4, stream>>>(e_src, e_dst, E, gcnt_u, gcnt_m, nbu, nbm);
  k_bscan<<<1, 256, 0, stream>>>(gcnt_u, gcnt_m, nbu, nbm, E, boff_u, boff_m, gcur_u, gcur_m);
  k_bscat<<<2 * nchunks, 256, (size_t)(2 * nbu) * 4, stream>>>(e_src, e_dst, E, gcur_u, gcur_m,
                                                               pk_u, pk_m, nbu, nbm, nchunks);
  k_bbuild<<<nbu + nbm, 512, 0, stream>>>(pk_u, pk_m, boff_u, boff_m, nbu, nbm, U, M, E,
                                          csr_u, csr_m, off_u, off_m);

  // ---- merged prep (bf16 tables + combined classifier weights) ----
  int gProj = (M * H + 255) / 256;
  int gCvt  = (U * 16 + 255) / 256;
  k_prep<<<gProj + gCvt + 8, 256, 0, stream>>>(
      movie_x, w_movie, b_movie, movie_emb, mnid, user_emb, unid,
      l2v_Wl, l2v_Wr, l2v_bl, l2r_Wl, l2r_Wr, l2r_bl, cls_W,
      xm_bf, xu_bf, cw, M, U, gProj, gCvt);

  // ---- merged layer-1 (MFMA) fused with classifier projection ----
  int gU_s = (U + 127) / 128;
  int gM_s = (M + 127) / 128;
  k_sage_mfma<<<gU_s + gM_s, 512, 0, stream>>>(
      xu_bf, xm_bf, csr_u, off_u, csr_m, off_m,
      l1v_Wl, l1v_bl, l1v_Wr,
      l1r_Wl, l1r_bl, l1r_Wr,
      CWml, CWur, CWul, CWmr,
      Zu, Zm, U, M, E, gU_s);

  // ---- merged layer-2 aggregation ----
  int gU_a = (U + 255) / 256;
  int gM_a = (M + 255) / 256;
  k_agg7m<<<gU_a + gM_a, 256, 0, stream>>>(Zu, Zm, csr_u, off_u, csr_m, off_m,
                                           cbu, cbm, Pu, Pm, U, M, gU_a);

  // ---- final ----
  int total = EL * C;
  k_final<<<(total + 255) / 256, 256, 0, stream>>>(el_src, el_dst, Pu, Pm, cls_b, (float*)d_out, total);
}